// Round 3
// baseline (1251.817 us; speedup 1.0000x reference)
//
#include <hip/hip_runtime.h>
#include <hip/hip_fp16.h>
#include <math.h>

#define T 512              // threads per block (8 waves)
#define R 8                // anchor rows per block
#define BB 4096            // batch size
#define DD 128             // feature dim
#define NQ (DD/4)          // 32 float4 quads per row

constexpr float POS_W  = 2.0f;
constexpr float NEG_W  = 40.0f;
constexpr float MARGIN = 0.1f;
constexpr float THRESH = 0.5f;
constexpr float INV_TAU = 0.25f;
constexpr float BETA   = 0.5f;

__device__ __forceinline__ float dot4(float4 a, float4 b) {
  return a.x*b.x + a.y*b.y + a.z*b.z + a.w*b.w;
}

template<int OPK>  // 0=sum 1=min 2=max
__device__ __forceinline__ float wred(float v) {
#pragma unroll
  for (int o = 32; o; o >>= 1) {
    float t = __shfl_xor(v, o);
    v = (OPK == 0) ? (v + t) : (OPK == 1 ? fminf(v, t) : fmaxf(v, t));
  }
  return v;
}

#define REDUCE_R(arr, OPK, OUTS) do {                                        \
  _Pragma("unroll")                                                          \
  for (int r_ = 0; r_ < R; ++r_) {                                           \
    float v_ = wred<OPK>(arr[r_]);                                           \
    if (lane == 0) red[wid][r_] = v_;                                        \
  }                                                                          \
  __syncthreads();                                                           \
  if (tid < R) {                                                             \
    float x_ = red[0][tid];                                                  \
    _Pragma("unroll")                                                        \
    for (int w_ = 1; w_ < T/64; ++w_) {                                      \
      float t_ = red[w_][tid];                                               \
      x_ = (OPK == 0) ? (x_ + t_) : (OPK == 1 ? fminf(x_, t_) : fmaxf(x_, t_)); \
    }                                                                        \
    OUTS[tid] = x_;                                                          \
  }                                                                          \
  __syncthreads();                                                           \
} while (0)

__global__ __launch_bounds__(T, 4) void crit_main(
    const float* __restrict__ batch,
    const float* __restrict__ teacher,
    const int*   __restrict__ labels,
    double*      __restrict__ acc,
    int*         __restrict__ nvalid)
{
  // dynamic LDS: retained sims as half2, [32 slots][T] -> conflict-free stride
  extern __shared__ __half2 sSim[];   // 32*512*4B = 64 KB

  __shared__ float4 sA[R][NQ];
  __shared__ float4 sT[R][NQ];
  __shared__ int    sLab[R];
  __shared__ float  red[T/64][R];
  __shared__ float  sMP[R], sMN[R], sZS[R], sZT[R], sW[R], sPS[R], sNS[R];

  const int tid  = threadIdx.x;
  const int lane = tid & 63;
  const int wid  = tid >> 6;
  const int i0   = blockIdx.x * R;

  const float4* b4 = reinterpret_cast<const float4*>(batch);
  const float4* t4 = reinterpret_cast<const float4*>(teacher);

  for (int idx = tid; idx < R*NQ; idx += T) {
    int r = idx / NQ, q = idx % NQ;
    sA[r][q] = b4[(size_t)(i0 + r) * NQ + q];
    sT[r][q] = t4[(size_t)(i0 + r) * NQ + q];
  }
  if (tid < R) sLab[tid] = labels[i0 + tid];
  __syncthreads();

  int labR[R];
#pragma unroll
  for (int r = 0; r < R; ++r) labR[r] = sLab[r];

  int   jlab[8];
  float zs[R], mp[R], mn[R];
#pragma unroll
  for (int r = 0; r < R; ++r) {
    zs[r] = 0.f; mp[r] = INFINITY; mn[r] = -INFINITY;
  }

  // =============== Phase A: batch sims -> LDS(half2) + stats ===============
#pragma unroll
  for (int g = 0; g < 2; ++g) {
    float accS[4][R];
#pragma unroll
    for (int u = 0; u < 4; ++u)
#pragma unroll
      for (int r = 0; r < R; ++r) accS[u][r] = 0.f;

    const int jb = tid + T*4*g;
#pragma unroll
    for (int u = 0; u < 4; ++u) jlab[4*g + u] = labels[jb + T*u];

    const float4* br0 = b4 + (size_t)jb * NQ;

#pragma unroll 1
    for (int kc = 0; kc < NQ/4; ++kc) {
#pragma unroll
      for (int up = 0; up < 2; ++up) {
        const int u0 = 2*up, u1 = 2*up + 1;
        float4 bq0[4], bq1[4];
#pragma unroll
        for (int q = 0; q < 4; ++q) bq0[q] = br0[(size_t)(T*u0)*NQ + kc*4 + q];
#pragma unroll
        for (int q = 0; q < 4; ++q) bq1[q] = br0[(size_t)(T*u1)*NQ + kc*4 + q];
#pragma unroll
        for (int q = 0; q < 4; ++q) {
#pragma unroll
          for (int r = 0; r < R; ++r) {
            float4 a = sA[r][kc*4 + q];
            accS[u0][r] += dot4(a, bq0[q]);
            accS[u1][r] += dot4(a, bq1[q]);
          }
        }
      }
    }

#pragma unroll
    for (int u = 0; u < 4; ++u) {
      const int p  = 4*g + u;
      const int j  = tid + T*p;
      const int lj = jlab[p];
#pragma unroll
      for (int r = 0; r < R; ++r) {
        float sim = accS[u][r];
        bool same = (lj == labR[r]);
        float s   = sim * (same ? INV_TAU : BETA*INV_TAU);
        zs[r] += __expf(s);
        if (same) {
          if (j != i0 + r) mp[r] = fminf(mp[r], sim);
        } else {
          mn[r] = fmaxf(mn[r], sim);
        }
      }
      // stash raw sims to LDS as half2 pairs
#pragma unroll
      for (int rr = 0; rr < 4; ++rr) {
        __half2 h2;
        h2.x = __float2half(accS[u][2*rr]);
        h2.y = __float2half(accS[u][2*rr+1]);
        sSim[(p*4 + rr)*T + tid] = h2;
      }
    }
  }

  REDUCE_R(mp, 1, sMP);
  REDUCE_R(mn, 2, sMN);
  REDUCE_R(zs, 0, sZS);

  // =============== Phase B: teacher sims + KD ===============
  float zt[R], wv[R];
#pragma unroll
  for (int r = 0; r < R; ++r) { zt[r] = 0.f; wv[r] = 0.f; }

#pragma unroll
  for (int g = 0; g < 2; ++g) {
    float accT[4][R];
#pragma unroll
    for (int u = 0; u < 4; ++u)
#pragma unroll
      for (int r = 0; r < R; ++r) accT[u][r] = 0.f;

    const int jb = tid + T*4*g;
    const float4* tr0 = t4 + (size_t)jb * NQ;

#pragma unroll 1
    for (int kc = 0; kc < NQ/4; ++kc) {
#pragma unroll
      for (int up = 0; up < 2; ++up) {
        const int u0 = 2*up, u1 = 2*up + 1;
        float4 tq0[4], tq1[4];
#pragma unroll
        for (int q = 0; q < 4; ++q) tq0[q] = tr0[(size_t)(T*u0)*NQ + kc*4 + q];
#pragma unroll
        for (int q = 0; q < 4; ++q) tq1[q] = tr0[(size_t)(T*u1)*NQ + kc*4 + q];
#pragma unroll
        for (int q = 0; q < 4; ++q) {
#pragma unroll
          for (int r = 0; r < R; ++r) {
            float4 a = sT[r][kc*4 + q];
            accT[u0][r] += dot4(a, tq0[q]);
            accT[u1][r] += dot4(a, tq1[q]);
          }
        }
      }
    }

#pragma unroll
    for (int u = 0; u < 4; ++u) {
      const int p  = 4*g + u;
      const int lj = jlab[p];
      float sraw[R];
#pragma unroll
      for (int rr = 0; rr < 4; ++rr) {
        __half2 h2 = sSim[(p*4 + rr)*T + tid];
        sraw[2*rr]   = __half2float(h2.x);
        sraw[2*rr+1] = __half2float(h2.y);
      }
#pragma unroll
      for (int r = 0; r < R; ++r) {
        float tsim = accT[u][r];
        bool same  = (lj == labR[r]);
        float scale = (same ? INV_TAU : BETA*INV_TAU);
        float s  = sraw[r] * scale;
        float ts = tsim * scale;
        float et = __expf(ts);
        zt[r] += et;
        wv[r] += et * (ts - s);
      }
    }
  }

  REDUCE_R(zt, 0, sZT);
  REDUCE_R(wv, 0, sW);

  // =============== pass 2: masked rank sums from LDS sims ===============
  float ps[R], ns[R];
#pragma unroll
  for (int r = 0; r < R; ++r) { ps[r] = 0.f; ns[r] = 0.f; }
#pragma unroll
  for (int p = 0; p < 8; ++p) {
    const int j  = tid + T*p;
    const int lj = jlab[p];
    float sraw[R];
#pragma unroll
    for (int rr = 0; rr < 4; ++rr) {
      __half2 h2 = sSim[(p*4 + rr)*T + tid];
      sraw[2*rr]   = __half2float(h2.x);
      sraw[2*rr+1] = __half2float(h2.y);
    }
#pragma unroll
    for (int r = 0; r < R; ++r) {
      float sim = sraw[r];
      if (lj == labR[r]) {
        if (j != i0 + r && (sim - MARGIN < sMN[r]))
          ps[r] += __expf(-POS_W * (sim - THRESH));
      } else {
        if (sim + MARGIN > sMP[r])
          ns[r] += __expf(NEG_W * (sim - THRESH));
      }
    }
  }
  REDUCE_R(ps, 0, sPS);
  REDUCE_R(ns, 0, sNS);

  if (tid < R) {
    float kl = sW[tid] / sZT[tid] + __logf(sZS[tid]) - __logf(sZT[tid]);
    atomicAdd(&acc[1], (double)kl);

    float psum = sPS[tid], nsum = sNS[tid];
    if (psum > 0.f && nsum > 0.f) {
      float term = log1pf(psum) * (1.0f/POS_W) + log1pf(nsum) * (1.0f/NEG_W);
      atomicAdd(&acc[0], (double)term);
      atomicAdd(nvalid, 1);
    }
  }
}

__global__ void crit_final(const double* __restrict__ acc,
                           const int*    __restrict__ nvalid,
                           const int*    __restrict__ epoch,
                           float*        __restrict__ out)
{
  int nv = *nvalid;
  double loss_rank = acc[0] / (double)(nv < 1 ? 1 : nv);
  double loss_kd   = acc[1] / (double)BB;
  double wgt = ((double)(*epoch)) * 0.01 * 16.0;
  out[0] = (float)(loss_rank + wgt * loss_kd);
  out[1] = (float)loss_rank;
  out[2] = (float)loss_kd;
}

extern "C" void kernel_launch(void* const* d_in, const int* in_sizes, int n_in,
                              void* d_out, int out_size, void* d_ws, size_t ws_size,
                              hipStream_t stream)
{
  (void)in_sizes; (void)n_in; (void)out_size; (void)ws_size;
  const float* batch   = (const float*)d_in[0];
  const float* teacher = (const float*)d_in[1];
  const int*   labels  = (const int*)d_in[2];
  const int*   epoch   = (const int*)d_in[3];
  float* out  = (float*)d_out;
  double* acc = (double*)d_ws;
  int* nv     = (int*)((char*)d_ws + 16);

  hipMemsetAsync(d_ws, 0, 32, stream);
  const size_t dynls = (size_t)32 * T * sizeof(__half2);   // 64 KB
  crit_main<<<dim3(BB / R), dim3(T), dynls, stream>>>(batch, teacher, labels, acc, nv);
  crit_final<<<dim3(1), dim3(1), 0, stream>>>(acc, nv, epoch, out);
}

// Round 4
// 506.836 us; speedup vs baseline: 2.4699x; 2.4699x over previous
//
#include <hip/hip_runtime.h>
#include <hip/hip_fp16.h>
#include <math.h>

#define T 512              // threads per block (8 waves)
#define R 8                // anchor rows per block
#define BB 4096            // batch size
#define DD 128             // feature dim
#define NQ (DD/4)          // 32 float4 quads per row

constexpr float POS_W  = 2.0f;
constexpr float NEG_W  = 40.0f;
constexpr float MARGIN = 0.1f;
constexpr float THRESH = 0.5f;
constexpr float INV_TAU = 0.25f;
constexpr float BETA   = 0.5f;

__device__ __forceinline__ float dot4(float4 a, float4 b) {
  return a.x*b.x + a.y*b.y + a.z*b.z + a.w*b.w;
}

template<int OPK>  // 0=sum 1=min 2=max
__device__ __forceinline__ float wred(float v) {
#pragma unroll
  for (int o = 32; o; o >>= 1) {
    float t = __shfl_xor(v, o);
    v = (OPK == 0) ? (v + t) : (OPK == 1 ? fminf(v, t) : fmaxf(v, t));
  }
  return v;
}

#define REDUCE_R(arr, OPK, OUTS) do {                                        \
  _Pragma("unroll")                                                          \
  for (int r_ = 0; r_ < R; ++r_) {                                           \
    float v_ = wred<OPK>(arr[r_]);                                           \
    if (lane == 0) red[wid][r_] = v_;                                        \
  }                                                                          \
  __syncthreads();                                                           \
  if (tid < R) {                                                             \
    float x_ = red[0][tid];                                                  \
    _Pragma("unroll")                                                        \
    for (int w_ = 1; w_ < T/64; ++w_) {                                      \
      float t_ = red[w_][tid];                                               \
      x_ = (OPK == 0) ? (x_ + t_) : (OPK == 1 ? fminf(x_, t_) : fmaxf(x_, t_)); \
    }                                                                        \
    OUTS[tid] = x_;                                                          \
  }                                                                          \
  __syncthreads();                                                           \
} while (0)

// ================= kernel A: batch GEMM -> sim(fp16) + min/max/Zs =========
__global__ __launch_bounds__(T, 2) void kA(
    const float* __restrict__ batch,
    const int*   __restrict__ labels,
    __half2*     __restrict__ simh,      // [BB/2][BB] packed row pairs
    float* __restrict__ mpg, float* __restrict__ mng, float* __restrict__ zsg)
{
  __shared__ float4 sA[R][NQ];
  __shared__ int    sLab[R];
  __shared__ float  red[T/64][R];
  __shared__ float  sMP[R], sMN[R], sZS[R];

  const int tid  = threadIdx.x;
  const int lane = tid & 63;
  const int wid  = tid >> 6;
  const int i0   = blockIdx.x * R;

  const float4* b4 = reinterpret_cast<const float4*>(batch);

  for (int idx = tid; idx < R*NQ; idx += T) {
    int r = idx / NQ, q = idx % NQ;
    sA[r][q] = b4[(size_t)(i0 + r) * NQ + q];
  }
  if (tid < R) sLab[tid] = labels[i0 + tid];
  __syncthreads();

  int labR[R];
#pragma unroll
  for (int r = 0; r < R; ++r) labR[r] = sLab[r];

  float zs[R], mp[R], mn[R];
#pragma unroll
  for (int r = 0; r < R; ++r) { zs[r] = 0.f; mp[r] = INFINITY; mn[r] = -INFINITY; }

#pragma unroll 1
  for (int g = 0; g < 2; ++g) {
    float accS[4][R];
#pragma unroll
    for (int u = 0; u < 4; ++u)
#pragma unroll
      for (int r = 0; r < R; ++r) accS[u][r] = 0.f;

    const int jb = tid + T*4*g;
    int jlab[4];
#pragma unroll
    for (int u = 0; u < 4; ++u) jlab[u] = labels[jb + T*u];

    const float4* br0 = b4 + (size_t)jb * NQ;

#pragma unroll 1
    for (int kc = 0; kc < NQ/4; ++kc) {
#pragma unroll
      for (int up = 0; up < 2; ++up) {
        const int u0 = 2*up, u1 = 2*up + 1;
        float4 bq0[4], bq1[4];
#pragma unroll
        for (int q = 0; q < 4; ++q) bq0[q] = br0[(size_t)(T*u0)*NQ + kc*4 + q];
#pragma unroll
        for (int q = 0; q < 4; ++q) bq1[q] = br0[(size_t)(T*u1)*NQ + kc*4 + q];
#pragma unroll
        for (int q = 0; q < 4; ++q) {
#pragma unroll
          for (int r = 0; r < R; ++r) {
            float4 a = sA[r][kc*4 + q];
            accS[u0][r] += dot4(a, bq0[q]);
            accS[u1][r] += dot4(a, bq1[q]);
          }
        }
      }
    }

#pragma unroll
    for (int u = 0; u < 4; ++u) {
      const int j  = jb + T*u;
      const int lj = jlab[u];
#pragma unroll
      for (int r = 0; r < R; ++r) {
        float sim = accS[u][r];
        bool same = (lj == labR[r]);
        zs[r] += __expf(sim * (same ? INV_TAU : BETA*INV_TAU));
        if (same) {
          if (j != i0 + r) mp[r] = fminf(mp[r], sim);
        } else {
          mn[r] = fmaxf(mn[r], sim);
        }
      }
#pragma unroll
      for (int rr = 0; rr < 4; ++rr) {
        __half2 h2;
        h2.x = __float2half(accS[u][2*rr]);
        h2.y = __float2half(accS[u][2*rr+1]);
        simh[(size_t)(i0/2 + rr) * BB + j] = h2;
      }
    }
  }

  REDUCE_R(mp, 1, sMP);
  REDUCE_R(mn, 2, sMN);
  REDUCE_R(zs, 0, sZS);
  if (tid < R) {
    mpg[i0 + tid] = sMP[tid];
    mng[i0 + tid] = sMN[tid];
    zsg[i0 + tid] = sZS[tid];
  }
}

// ================= kernel B: teacher GEMM -> Zt, W ========================
__global__ __launch_bounds__(T, 2) void kB(
    const float* __restrict__ teacher,
    const int*   __restrict__ labels,
    const __half2* __restrict__ simh,
    float* __restrict__ ztg, float* __restrict__ wvg)
{
  __shared__ float4 sT[R][NQ];
  __shared__ int    sLab[R];
  __shared__ float  red[T/64][R];
  __shared__ float  sZT[R], sW[R];

  const int tid  = threadIdx.x;
  const int lane = tid & 63;
  const int wid  = tid >> 6;
  const int i0   = blockIdx.x * R;

  const float4* t4 = reinterpret_cast<const float4*>(teacher);

  for (int idx = tid; idx < R*NQ; idx += T) {
    int r = idx / NQ, q = idx % NQ;
    sT[r][q] = t4[(size_t)(i0 + r) * NQ + q];
  }
  if (tid < R) sLab[tid] = labels[i0 + tid];
  __syncthreads();

  int labR[R];
#pragma unroll
  for (int r = 0; r < R; ++r) labR[r] = sLab[r];

  float zt[R], wv[R];
#pragma unroll
  for (int r = 0; r < R; ++r) { zt[r] = 0.f; wv[r] = 0.f; }

#pragma unroll 1
  for (int g = 0; g < 2; ++g) {
    float accT[4][R];
#pragma unroll
    for (int u = 0; u < 4; ++u)
#pragma unroll
      for (int r = 0; r < R; ++r) accT[u][r] = 0.f;

    const int jb = tid + T*4*g;
    int jlab[4];
#pragma unroll
    for (int u = 0; u < 4; ++u) jlab[u] = labels[jb + T*u];

    const float4* tr0 = t4 + (size_t)jb * NQ;

#pragma unroll 1
    for (int kc = 0; kc < NQ/4; ++kc) {
#pragma unroll
      for (int up = 0; up < 2; ++up) {
        const int u0 = 2*up, u1 = 2*up + 1;
        float4 tq0[4], tq1[4];
#pragma unroll
        for (int q = 0; q < 4; ++q) tq0[q] = tr0[(size_t)(T*u0)*NQ + kc*4 + q];
#pragma unroll
        for (int q = 0; q < 4; ++q) tq1[q] = tr0[(size_t)(T*u1)*NQ + kc*4 + q];
#pragma unroll
        for (int q = 0; q < 4; ++q) {
#pragma unroll
          for (int r = 0; r < R; ++r) {
            float4 a = sT[r][kc*4 + q];
            accT[u0][r] += dot4(a, tq0[q]);
            accT[u1][r] += dot4(a, tq1[q]);
          }
        }
      }
    }

#pragma unroll
    for (int u = 0; u < 4; ++u) {
      const int j  = jb + T*u;
      const int lj = jlab[u];
      float sraw[R];
#pragma unroll
      for (int rr = 0; rr < 4; ++rr) {
        __half2 h2 = simh[(size_t)(i0/2 + rr) * BB + j];
        sraw[2*rr]   = __half2float(h2.x);
        sraw[2*rr+1] = __half2float(h2.y);
      }
#pragma unroll
      for (int r = 0; r < R; ++r) {
        bool same   = (lj == labR[r]);
        float scale = same ? INV_TAU : BETA*INV_TAU;
        float ts = accT[u][r] * scale;
        float s  = sraw[r] * scale;
        float et = __expf(ts);
        zt[r] += et;
        wv[r] += et * (ts - s);
      }
    }
  }

  REDUCE_R(zt, 0, sZT);
  REDUCE_R(wv, 0, sW);
  if (tid < R) {
    ztg[i0 + tid] = sZT[tid];
    wvg[i0 + tid] = sW[tid];
  }
}

// ================= kernel C: masked rank sums from sim(fp16) ==============
__global__ __launch_bounds__(T, 2) void kC(
    const int*     __restrict__ labels,
    const __half2* __restrict__ simh,
    const float* __restrict__ mpg, const float* __restrict__ mng,
    float* __restrict__ psg, float* __restrict__ nsg)
{
  __shared__ int   sLab[R];
  __shared__ float red[T/64][R];
  __shared__ float sMP[R], sMN[R], sPS[R], sNS[R];

  const int tid  = threadIdx.x;
  const int lane = tid & 63;
  const int wid  = tid >> 6;
  const int i0   = blockIdx.x * R;

  if (tid < R) {
    sLab[tid] = labels[i0 + tid];
    sMP[tid]  = mpg[i0 + tid];
    sMN[tid]  = mng[i0 + tid];
  }
  __syncthreads();

  int labR[R]; float mpr[R], mnr[R];
#pragma unroll
  for (int r = 0; r < R; ++r) { labR[r] = sLab[r]; mpr[r] = sMP[r]; mnr[r] = sMN[r]; }

  float ps[R], ns[R];
#pragma unroll
  for (int r = 0; r < R; ++r) { ps[r] = 0.f; ns[r] = 0.f; }

#pragma unroll 1
  for (int p = 0; p < 8; ++p) {
    const int j  = tid + T*p;
    const int lj = labels[j];
    float sraw[R];
#pragma unroll
    for (int rr = 0; rr < 4; ++rr) {
      __half2 h2 = simh[(size_t)(i0/2 + rr) * BB + j];
      sraw[2*rr]   = __half2float(h2.x);
      sraw[2*rr+1] = __half2float(h2.y);
    }
#pragma unroll
    for (int r = 0; r < R; ++r) {
      float sim = sraw[r];
      if (lj == labR[r]) {
        if (j != i0 + r && (sim - MARGIN < mnr[r]))
          ps[r] += __expf(-POS_W * (sim - THRESH));
      } else {
        if (sim + MARGIN > mpr[r])
          ns[r] += __expf(NEG_W * (sim - THRESH));
      }
    }
  }
  REDUCE_R(ps, 0, sPS);
  REDUCE_R(ns, 0, sNS);
  if (tid < R) {
    psg[i0 + tid] = sPS[tid];
    nsg[i0 + tid] = sNS[tid];
  }
}

// ================= kernel D: finalize =====================================
__global__ __launch_bounds__(T, 1) void kD(
    const float* __restrict__ zsg, const float* __restrict__ ztg,
    const float* __restrict__ wvg, const float* __restrict__ psg,
    const float* __restrict__ nsg, const int* __restrict__ epoch,
    float* __restrict__ out)
{
  __shared__ double sRank[T/64], sKd[T/64];
  __shared__ int    sNv[T/64];

  const int tid  = threadIdx.x;
  const int lane = tid & 63;
  const int wid  = tid >> 6;

  double rank = 0.0, kd = 0.0;
  int nv = 0;
  for (int i = tid; i < BB; i += T) {
    float zt = ztg[i];
    kd += (double)(wvg[i] / zt + __logf(zsg[i]) - __logf(zt));
    float p = psg[i], n = nsg[i];
    if (p > 0.f && n > 0.f) {
      rank += (double)(log1pf(p) * (1.0f/POS_W) + log1pf(n) * (1.0f/NEG_W));
      nv++;
    }
  }
#pragma unroll
  for (int o = 32; o; o >>= 1) {
    rank += __shfl_xor(rank, o);
    kd   += __shfl_xor(kd, o);
    nv   += __shfl_xor(nv, o);
  }
  if (lane == 0) { sRank[wid] = rank; sKd[wid] = kd; sNv[wid] = nv; }
  __syncthreads();
  if (tid == 0) {
    double R_ = 0.0, K_ = 0.0; int N_ = 0;
    for (int w = 0; w < T/64; ++w) { R_ += sRank[w]; K_ += sKd[w]; N_ += sNv[w]; }
    double loss_rank = R_ / (double)(N_ < 1 ? 1 : N_);
    double loss_kd   = K_ / (double)BB;
    double wgt = (double)epoch[0] * 0.16;   // epoch/100 * ALPHA * TAU^2
    out[0] = (float)(loss_rank + wgt * loss_kd);
    out[1] = (float)loss_rank;
    out[2] = (float)loss_kd;
  }
}

extern "C" void kernel_launch(void* const* d_in, const int* in_sizes, int n_in,
                              void* d_out, int out_size, void* d_ws, size_t ws_size,
                              hipStream_t stream)
{
  (void)in_sizes; (void)n_in; (void)out_size; (void)ws_size;
  const float* batch   = (const float*)d_in[0];
  const float* teacher = (const float*)d_in[1];
  const int*   labels  = (const int*)d_in[2];
  const int*   epoch   = (const int*)d_in[3];
  float* out = (float*)d_out;

  char* w = (char*)d_ws;
  __half2* simh = (__half2*)w;                          // 2048*4096*4B = 33.5 MB
  float* mpg = (float*)(w + (size_t)33554432);
  float* mng = mpg + BB;
  float* zsg = mpg + 2*BB;
  float* ztg = mpg + 3*BB;
  float* wvg = mpg + 4*BB;
  float* psg = mpg + 5*BB;
  float* nsg = mpg + 6*BB;

  kA<<<dim3(BB/R), dim3(T), 0, stream>>>(batch, labels, simh, mpg, mng, zsg);
  kB<<<dim3(BB/R), dim3(T), 0, stream>>>(teacher, labels, simh, ztg, wvg);
  kC<<<dim3(BB/R), dim3(T), 0, stream>>>(labels, simh, mpg, mng, psg, nsg);
  kD<<<dim3(1), dim3(T), 0, stream>>>(zsg, ztg, wvg, psg, nsg, epoch, out);
}

// Round 5
// 203.417 us; speedup vs baseline: 6.1539x; 2.4916x over previous
//
#include <hip/hip_runtime.h>
#include <math.h>

#define BB 4096
#define DD 128
#define T  512

typedef __attribute__((ext_vector_type(8))) short short8;
typedef __attribute__((ext_vector_type(4))) float f32x4;

constexpr float POS_W  = 2.0f;
constexpr float NEG_W  = 40.0f;
constexpr float MARGIN = 0.1f;
constexpr float THRESH = 0.5f;

__device__ __forceinline__ unsigned short f2bf(float f) {
  unsigned int u = __float_as_uint(f);
  return (unsigned short)((u + 0x7fffu + ((u >> 16) & 1u)) >> 16);
}
__device__ __forceinline__ float bf2f(unsigned short h) {
  return __uint_as_float(((unsigned int)h) << 16);
}

__device__ __forceinline__ f32x4 mfma16(short8 a, short8 b, f32x4 c) {
  return __builtin_amdgcn_mfma_f32_16x16x32_bf16(a, b, c, 0, 0, 0);
}

// ============ k0: fp32 -> bf16 hi/lo split for batch & teacher ============
__global__ __launch_bounds__(256) void k0(
    const float* __restrict__ b, const float* __restrict__ t,
    unsigned short* __restrict__ bh, unsigned short* __restrict__ bl,
    unsigned short* __restrict__ th, unsigned short* __restrict__ tl)
{
  const int i = blockIdx.x * 256 + threadIdx.x;   // < BB*DD/4 = 131072
  {
    float4 v = reinterpret_cast<const float4*>(b)[i];
    ushort4 h, l;
    h.x = f2bf(v.x); l.x = f2bf(v.x - bf2f(h.x));
    h.y = f2bf(v.y); l.y = f2bf(v.y - bf2f(h.y));
    h.z = f2bf(v.z); l.z = f2bf(v.z - bf2f(h.z));
    h.w = f2bf(v.w); l.w = f2bf(v.w - bf2f(h.w));
    reinterpret_cast<ushort4*>(bh)[i] = h;
    reinterpret_cast<ushort4*>(bl)[i] = l;
  }
  {
    float4 v = reinterpret_cast<const float4*>(t)[i];
    ushort4 h, l;
    h.x = f2bf(v.x); l.x = f2bf(v.x - bf2f(h.x));
    h.y = f2bf(v.y); l.y = f2bf(v.y - bf2f(h.y));
    h.z = f2bf(v.z); l.z = f2bf(v.z - bf2f(h.z));
    h.w = f2bf(v.w); l.w = f2bf(v.w - bf2f(h.w));
    reinterpret_cast<ushort4*>(th)[i] = h;
    reinterpret_cast<ushort4*>(tl)[i] = l;
  }
}

// ============ kA: batch MFMA Gram -> min_pos / max_neg / Zs ===============
__global__ __launch_bounds__(T, 2) void kA(
    const unsigned short* __restrict__ xh,
    const unsigned short* __restrict__ xl,
    const int* __restrict__ labels,
    float* __restrict__ mpg, float* __restrict__ mng, float* __restrict__ zsg)
{
  __shared__ int   sLab[BB];          // 16 KB
  __shared__ float sMP[8][16], sMN[8][16], sZS[8][16];

  const int tid  = threadIdx.x;
  const int lane = tid & 63;
  const int wid  = tid >> 6;
  const int i0   = blockIdx.x * 16;
  const int l15  = lane & 15;
  const int rbase = (lane >> 4) * 4;
  const int koff  = (lane >> 4) * 8;

  for (int i = tid; i < BB; i += T) sLab[i] = labels[i];
  __syncthreads();

  // anchor A-fragments (hi/lo), 16 rows, K=128 in 4 steps of 32
  short8 Ah[4], Al[4];
  {
    const size_t abase = (size_t)(i0 + l15) * DD + koff;
#pragma unroll
    for (int s = 0; s < 4; ++s) {
      Ah[s] = *reinterpret_cast<const short8*>(xh + abase + s * 32);
      Al[s] = *reinterpret_cast<const short8*>(xl + abase + s * 32);
    }
  }
  int labA[4];
#pragma unroll
  for (int r = 0; r < 4; ++r) labA[r] = sLab[i0 + rbase + r];

  float mp[4], mn[4], zs[4];
#pragma unroll
  for (int r = 0; r < 4; ++r) { mp[r] = INFINITY; mn[r] = -INFINITY; zs[r] = 0.f; }

  // each wave: panels p, p+8 per iter (ILP-2), 8 waves cover 256 panels
#pragma unroll 1
  for (int p = wid; p < 256; p += 16) {
    const int pA = p, pB = p + 8;
    const size_t b0 = (size_t)(pA * 16 + l15) * DD + koff;
    const size_t b1 = (size_t)(pB * 16 + l15) * DD + koff;
    short8 B0h[4], B0l[4], B1h[4], B1l[4];
#pragma unroll
    for (int s = 0; s < 4; ++s) {
      B0h[s] = *reinterpret_cast<const short8*>(xh + b0 + s * 32);
      B0l[s] = *reinterpret_cast<const short8*>(xl + b0 + s * 32);
      B1h[s] = *reinterpret_cast<const short8*>(xh + b1 + s * 32);
      B1l[s] = *reinterpret_cast<const short8*>(xl + b1 + s * 32);
    }
    f32x4 a0 = {0.f, 0.f, 0.f, 0.f}, a1 = {0.f, 0.f, 0.f, 0.f};
#pragma unroll
    for (int s = 0; s < 4; ++s) {
      a0 = mfma16(Ah[s], B0h[s], a0);
      a1 = mfma16(Ah[s], B1h[s], a1);
      a0 = mfma16(Al[s], B0h[s], a0);
      a1 = mfma16(Al[s], B1h[s], a1);
      a0 = mfma16(Ah[s], B0l[s], a0);
      a1 = mfma16(Ah[s], B1l[s], a1);
    }
#pragma unroll
    for (int t2 = 0; t2 < 2; ++t2) {
      const int jcol = (t2 ? pB : pA) * 16 + l15;
      const int lj   = sLab[jcol];
      f32x4 acc = t2 ? a1 : a0;
#pragma unroll
      for (int r = 0; r < 4; ++r) {
        float sim = acc[r];
        bool same = (lj == labA[r]);
        zs[r] += __expf(sim * (same ? 0.25f : 0.125f));
        if (same) {
          if (jcol != i0 + rbase + r) mp[r] = fminf(mp[r], sim);
        } else {
          mn[r] = fmaxf(mn[r], sim);
        }
      }
    }
  }

  // reduce across the 16 lanes of each group (anchors rbase..rbase+3)
#pragma unroll
  for (int r = 0; r < 4; ++r) {
#pragma unroll
    for (int m = 1; m < 16; m <<= 1) {
      mp[r] = fminf(mp[r], __shfl_xor(mp[r], m));
      mn[r] = fmaxf(mn[r], __shfl_xor(mn[r], m));
      zs[r] += __shfl_xor(zs[r], m);
    }
  }
  if (l15 == 0) {
#pragma unroll
    for (int r = 0; r < 4; ++r) {
      sMP[wid][rbase + r] = mp[r];
      sMN[wid][rbase + r] = mn[r];
      sZS[wid][rbase + r] = zs[r];
    }
  }
  __syncthreads();
  if (tid < 16) {
    float a = INFINITY, b = -INFINITY, c = 0.f;
    for (int w = 0; w < 8; ++w) {
      a = fminf(a, sMP[w][tid]);
      b = fmaxf(b, sMN[w][tid]);
      c += sZS[w][tid];
    }
    mpg[i0 + tid] = a;
    mng[i0 + tid] = b;
    zsg[i0 + tid] = c;
  }
}

// ============ kB: batch+teacher MFMA -> Zt, W, ps, ns =====================
__global__ __launch_bounds__(T, 2) void kB(
    const unsigned short* __restrict__ xh, const unsigned short* __restrict__ xl,
    const unsigned short* __restrict__ yh, const unsigned short* __restrict__ yl,
    const int* __restrict__ labels,
    const float* __restrict__ mpg, const float* __restrict__ mng,
    float* __restrict__ ztg, float* __restrict__ wvg,
    float* __restrict__ psg, float* __restrict__ nsg)
{
  __shared__ int   sLab[BB];
  __shared__ float sZT[8][16], sWV[8][16], sPS[8][16], sNS[8][16];

  const int tid  = threadIdx.x;
  const int lane = tid & 63;
  const int wid  = tid >> 6;
  const int i0   = blockIdx.x * 16;
  const int l15  = lane & 15;
  const int rbase = (lane >> 4) * 4;
  const int koff  = (lane >> 4) * 8;

  for (int i = tid; i < BB; i += T) sLab[i] = labels[i];
  __syncthreads();

  short8 Ah[4], Al[4], Th[4], Tl[4];
  {
    const size_t abase = (size_t)(i0 + l15) * DD + koff;
#pragma unroll
    for (int s = 0; s < 4; ++s) {
      Ah[s] = *reinterpret_cast<const short8*>(xh + abase + s * 32);
      Al[s] = *reinterpret_cast<const short8*>(xl + abase + s * 32);
      Th[s] = *reinterpret_cast<const short8*>(yh + abase + s * 32);
      Tl[s] = *reinterpret_cast<const short8*>(yl + abase + s * 32);
    }
  }
  int labA[4]; float mpA[4], mnA[4];
#pragma unroll
  for (int r = 0; r < 4; ++r) {
    labA[r] = sLab[i0 + rbase + r];
    mpA[r]  = mpg[i0 + rbase + r];
    mnA[r]  = mng[i0 + rbase + r];
  }

  float zt[4], wv[4], ps[4], ns[4];
#pragma unroll
  for (int r = 0; r < 4; ++r) { zt[r] = 0.f; wv[r] = 0.f; ps[r] = 0.f; ns[r] = 0.f; }

#pragma unroll 1
  for (int p = wid; p < 256; p += 8) {
    const int j0 = p * 16;
    const size_t bbase = (size_t)(j0 + l15) * DD + koff;
    short8 Bh[4], Bl[4], Uh[4], Ul[4];
#pragma unroll
    for (int s = 0; s < 4; ++s) {
      Bh[s] = *reinterpret_cast<const short8*>(xh + bbase + s * 32);
      Bl[s] = *reinterpret_cast<const short8*>(xl + bbase + s * 32);
      Uh[s] = *reinterpret_cast<const short8*>(yh + bbase + s * 32);
      Ul[s] = *reinterpret_cast<const short8*>(yl + bbase + s * 32);
    }
    f32x4 accS = {0.f, 0.f, 0.f, 0.f}, accT = {0.f, 0.f, 0.f, 0.f};
#pragma unroll
    for (int s = 0; s < 4; ++s) {
      accS = mfma16(Ah[s], Bh[s], accS);
      accT = mfma16(Th[s], Uh[s], accT);
      accS = mfma16(Al[s], Bh[s], accS);
      accT = mfma16(Tl[s], Uh[s], accT);
      accS = mfma16(Ah[s], Bl[s], accS);
      accT = mfma16(Th[s], Ul[s], accT);
    }
    const int jcol = j0 + l15;
    const int lj   = sLab[jcol];
#pragma unroll
    for (int r = 0; r < 4; ++r) {
      float sim = accS[r], ts0 = accT[r];
      bool same = (lj == labA[r]);
      float sc  = same ? 0.25f : 0.125f;
      float s   = sim * sc;
      float ts  = ts0 * sc;
      float et  = __expf(ts);
      zt[r] += et;
      wv[r] += et * (ts - s);
      if (same) {
        if (jcol != i0 + rbase + r && (sim - MARGIN < mnA[r]))
          ps[r] += __expf(-POS_W * (sim - THRESH));
      } else {
        if (sim + MARGIN > mpA[r])
          ns[r] += __expf(NEG_W * (sim - THRESH));
      }
    }
  }

#pragma unroll
  for (int r = 0; r < 4; ++r) {
#pragma unroll
    for (int m = 1; m < 16; m <<= 1) {
      zt[r] += __shfl_xor(zt[r], m);
      wv[r] += __shfl_xor(wv[r], m);
      ps[r] += __shfl_xor(ps[r], m);
      ns[r] += __shfl_xor(ns[r], m);
    }
  }
  if (l15 == 0) {
#pragma unroll
    for (int r = 0; r < 4; ++r) {
      sZT[wid][rbase + r] = zt[r];
      sWV[wid][rbase + r] = wv[r];
      sPS[wid][rbase + r] = ps[r];
      sNS[wid][rbase + r] = ns[r];
    }
  }
  __syncthreads();
  if (tid < 16) {
    float a = 0.f, b = 0.f, c = 0.f, d = 0.f;
    for (int w = 0; w < 8; ++w) {
      a += sZT[w][tid]; b += sWV[w][tid]; c += sPS[w][tid]; d += sNS[w][tid];
    }
    ztg[i0 + tid] = a;
    wvg[i0 + tid] = b;
    psg[i0 + tid] = c;
    nsg[i0 + tid] = d;
  }
}

// ============ kD: finalize ================================================
__global__ __launch_bounds__(T, 1) void kD(
    const float* __restrict__ zsg, const float* __restrict__ ztg,
    const float* __restrict__ wvg, const float* __restrict__ psg,
    const float* __restrict__ nsg, const int* __restrict__ epoch,
    float* __restrict__ out)
{
  __shared__ double sRank[T/64], sKd[T/64];
  __shared__ int    sNv[T/64];

  const int tid  = threadIdx.x;
  const int lane = tid & 63;
  const int wid  = tid >> 6;

  double rank = 0.0, kd = 0.0;
  int nv = 0;
  for (int i = tid; i < BB; i += T) {
    float zt = ztg[i];
    kd += (double)(wvg[i] / zt + __logf(zsg[i]) - __logf(zt));
    float p = psg[i], n = nsg[i];
    if (p > 0.f && n > 0.f) {
      rank += (double)(log1pf(p) * (1.0f/POS_W) + log1pf(n) * (1.0f/NEG_W));
      nv++;
    }
  }
#pragma unroll
  for (int o = 32; o; o >>= 1) {
    rank += __shfl_xor(rank, o);
    kd   += __shfl_xor(kd, o);
    nv   += __shfl_xor(nv, o);
  }
  if (lane == 0) { sRank[wid] = rank; sKd[wid] = kd; sNv[wid] = nv; }
  __syncthreads();
  if (tid == 0) {
    double R_ = 0.0, K_ = 0.0; int N_ = 0;
    for (int w = 0; w < T/64; ++w) { R_ += sRank[w]; K_ += sKd[w]; N_ += sNv[w]; }
    double loss_rank = R_ / (double)(N_ < 1 ? 1 : N_);
    double loss_kd   = K_ / (double)BB;
    double wgt = (double)epoch[0] * 0.16;   // epoch/100 * ALPHA * TAU^2
    out[0] = (float)(loss_rank + wgt * loss_kd);
    out[1] = (float)loss_rank;
    out[2] = (float)loss_kd;
  }
}

extern "C" void kernel_launch(void* const* d_in, const int* in_sizes, int n_in,
                              void* d_out, int out_size, void* d_ws, size_t ws_size,
                              hipStream_t stream)
{
  (void)in_sizes; (void)n_in; (void)out_size; (void)ws_size;
  const float* batch   = (const float*)d_in[0];
  const float* teacher = (const float*)d_in[1];
  const int*   labels  = (const int*)d_in[2];
  const int*   epoch   = (const int*)d_in[3];
  float* out = (float*)d_out;

  char* w = (char*)d_ws;
  const size_t MB = 1048576;
  unsigned short* bh = (unsigned short*)(w + 0*MB);   // 1 MB each
  unsigned short* bl = (unsigned short*)(w + 1*MB);
  unsigned short* th = (unsigned short*)(w + 2*MB);
  unsigned short* tl = (unsigned short*)(w + 3*MB);
  float* mpg = (float*)(w + 4*MB);
  float* mng = mpg + BB;
  float* zsg = mpg + 2*BB;
  float* ztg = mpg + 3*BB;
  float* wvg = mpg + 4*BB;
  float* psg = mpg + 5*BB;
  float* nsg = mpg + 6*BB;

  k0<<<dim3(BB*DD/4/256), dim3(256), 0, stream>>>(batch, teacher, bh, bl, th, tl);
  kA<<<dim3(BB/16), dim3(T), 0, stream>>>(bh, bl, labels, mpg, mng, zsg);
  kB<<<dim3(BB/16), dim3(T), 0, stream>>>(bh, bl, th, tl, labels, mpg, mng,
                                          ztg, wvg, psg, nsg);
  kD<<<dim3(1), dim3(T), 0, stream>>>(zsg, ztg, wvg, psg, nsg, epoch, out);
}

// Round 6
// 98.265 us; speedup vs baseline: 12.7392x; 2.0701x over previous
//
#include <hip/hip_runtime.h>
#include <math.h>

#define BB  4096
#define DD  128
#define NCH 16             // j-chunks
#define NP  (256/NCH)      // panels per chunk = 16
#define TB  256            // threads per block (4 waves)

typedef __attribute__((ext_vector_type(8))) short short8;
typedef __attribute__((ext_vector_type(4))) float f32x4;

constexpr float POS_W  = 2.0f;
constexpr float NEG_W  = 40.0f;
constexpr float MARGIN = 0.1f;
constexpr float THRESH = 0.5f;

__device__ __forceinline__ unsigned short f2bf(float f) {
  unsigned int u = __float_as_uint(f);
  return (unsigned short)((u + 0x7fffu + ((u >> 16) & 1u)) >> 16);
}
__device__ __forceinline__ float bf2f(unsigned short h) {
  return __uint_as_float(((unsigned int)h) << 16);
}
__device__ __forceinline__ f32x4 mfma16(short8 a, short8 b, f32x4 c) {
  return __builtin_amdgcn_mfma_f32_16x16x32_bf16(a, b, c, 0, 0, 0);
}

// ============ k0: fp32 -> bf16 hi/lo split =================================
__global__ __launch_bounds__(256) void k0(
    const float* __restrict__ b, const float* __restrict__ t,
    unsigned short* __restrict__ bh, unsigned short* __restrict__ bl,
    unsigned short* __restrict__ th, unsigned short* __restrict__ tl)
{
  const int i = blockIdx.x * 256 + threadIdx.x;   // < BB*DD/4 = 131072
  {
    float4 v = reinterpret_cast<const float4*>(b)[i];
    ushort4 h, l;
    h.x = f2bf(v.x); l.x = f2bf(v.x - bf2f(h.x));
    h.y = f2bf(v.y); l.y = f2bf(v.y - bf2f(h.y));
    h.z = f2bf(v.z); l.z = f2bf(v.z - bf2f(h.z));
    h.w = f2bf(v.w); l.w = f2bf(v.w - bf2f(h.w));
    reinterpret_cast<ushort4*>(bh)[i] = h;
    reinterpret_cast<ushort4*>(bl)[i] = l;
  }
  {
    float4 v = reinterpret_cast<const float4*>(t)[i];
    ushort4 h, l;
    h.x = f2bf(v.x); l.x = f2bf(v.x - bf2f(h.x));
    h.y = f2bf(v.y); l.y = f2bf(v.y - bf2f(h.y));
    h.z = f2bf(v.z); l.z = f2bf(v.z - bf2f(h.z));
    h.w = f2bf(v.w); l.w = f2bf(v.w - bf2f(h.w));
    reinterpret_cast<ushort4*>(th)[i] = h;
    reinterpret_cast<ushort4*>(tl)[i] = l;
  }
}

// ============ kA: batch Gram chunk -> mp/mn/zs partials ====================
// block = (ag, ch): 64 anchors (4 waves x 16), chunk of 16 panels (256 j's).
// LDS layout per array: quad index (s*4+hi)*16 + j  (matches frag reads).
__global__ __launch_bounds__(TB, 4) void kA(
    const unsigned short* __restrict__ xh,
    const unsigned short* __restrict__ xl,
    const int* __restrict__ labels,
    float* __restrict__ mpP, float* __restrict__ mnP, float* __restrict__ zsP)
{
  __shared__ unsigned short sB[2][2 * 2048];   // 16 KB: [buf][arr*2048 + q*8]
  __shared__ int sJlab[256];

  const int tid  = threadIdx.x;
  const int lane = tid & 63;
  const int wid  = tid >> 6;
  const int ag   = blockIdx.x & 63;
  const int ch   = blockIdx.x >> 6;
  const int i0w  = ag * 64 + wid * 16;
  const int l15  = lane & 15;
  const int hi_l = lane >> 4;
  const int rbase = hi_l * 4;
  const int koff  = hi_l * 8;
  const int j0ch  = ch * 256;

  sJlab[tid] = labels[j0ch + tid];

  // per-thread staging coords (arr = k after unroll; s = wid uniform)
  const int sj = (tid >> 2) & 15;
  const int sh = tid & 3;
  const int lofs = ((wid * 4 + sh) * 16 + sj) * 8;     // elem offset in array
  const int gofs = sj * DD + wid * 32 + sh * 8;        // elem offset at j0=0

  // anchor fragments
  short8 Ah[4], Al[4];
  {
    const size_t ab = (size_t)(i0w + l15) * DD + koff;
#pragma unroll
    for (int s = 0; s < 4; ++s) {
      Ah[s] = *reinterpret_cast<const short8*>(xh + ab + s * 32);
      Al[s] = *reinterpret_cast<const short8*>(xl + ab + s * 32);
    }
  }
  int labA[4];
#pragma unroll
  for (int r = 0; r < 4; ++r) labA[r] = labels[i0w + rbase + r];

  float mp[4], mn[4], zs[4];
#pragma unroll
  for (int r = 0; r < 4; ++r) { mp[r] = INFINITY; mn[r] = -INFINITY; zs[r] = 0.f; }

  short8 stg[2];
  // prologue: stage panel 0 into buf 0
#pragma unroll
  for (int k = 0; k < 2; ++k) {
    const unsigned short* g = (k ? xl : xh) + (size_t)j0ch * DD + gofs;
    stg[k] = *reinterpret_cast<const short8*>(g);
  }
#pragma unroll
  for (int k = 0; k < 2; ++k)
    *reinterpret_cast<short8*>(&sB[0][k * 2048 + lofs]) = stg[k];

#pragma unroll 1
  for (int pp = 0; pp < NP; ++pp) {
    const int cur = pp & 1;
    if (pp + 1 < NP) {
      const size_t gb = (size_t)(j0ch + (pp + 1) * 16) * DD + gofs;
#pragma unroll
      for (int k = 0; k < 2; ++k)
        stg[k] = *reinterpret_cast<const short8*>((k ? xl : xh) + gb);
    }
    __syncthreads();

    f32x4 acc = {0.f, 0.f, 0.f, 0.f};
#pragma unroll
    for (int s = 0; s < 4; ++s) {
      const int ro = ((s * 4 + hi_l) * 16 + l15) * 8;
      short8 vh = *reinterpret_cast<const short8*>(&sB[cur][ro]);
      short8 vl = *reinterpret_cast<const short8*>(&sB[cur][2048 + ro]);
      acc = mfma16(Ah[s], vh, acc);
      acc = mfma16(Al[s], vh, acc);
      acc = mfma16(Ah[s], vl, acc);
    }

    const int lj   = sJlab[pp * 16 + l15];
    const int jcol = j0ch + pp * 16 + l15;
#pragma unroll
    for (int r = 0; r < 4; ++r) {
      float sim = acc[r];
      bool same = (lj == labA[r]);
      zs[r] += __expf(sim * (same ? 0.25f : 0.125f));
      if (same) {
        if (jcol != i0w + rbase + r) mp[r] = fminf(mp[r], sim);
      } else {
        mn[r] = fmaxf(mn[r], sim);
      }
    }

    if (pp + 1 < NP) {
#pragma unroll
      for (int k = 0; k < 2; ++k)
        *reinterpret_cast<short8*>(&sB[cur ^ 1][k * 2048 + lofs]) = stg[k];
    }
  }

#pragma unroll
  for (int r = 0; r < 4; ++r)
#pragma unroll
    for (int m = 1; m < 16; m <<= 1) {
      mp[r] = fminf(mp[r], __shfl_xor(mp[r], m));
      mn[r] = fmaxf(mn[r], __shfl_xor(mn[r], m));
      zs[r] += __shfl_xor(zs[r], m);
    }
  if (l15 == 0) {
#pragma unroll
    for (int r = 0; r < 4; ++r) {
      const int i_r = i0w + rbase + r;
      mpP[ch * BB + i_r] = mp[r];
      mnP[ch * BB + i_r] = mn[r];
      zsP[ch * BB + i_r] = zs[r];
    }
  }
}

// ============ kB: batch+teacher Gram chunk -> zt/wv/ps/ns partials =========
__global__ __launch_bounds__(TB, 3) void kB(
    const unsigned short* __restrict__ xh, const unsigned short* __restrict__ xl,
    const unsigned short* __restrict__ yh, const unsigned short* __restrict__ yl,
    const int* __restrict__ labels,
    const float* __restrict__ mpP, const float* __restrict__ mnP,
    float* __restrict__ ztP, float* __restrict__ wvP,
    float* __restrict__ psP, float* __restrict__ nsP)
{
  __shared__ unsigned short sB[2][4 * 2048];   // 32 KB
  __shared__ int sJlab[256];

  const int tid  = threadIdx.x;
  const int lane = tid & 63;
  const int wid  = tid >> 6;
  const int ag   = blockIdx.x & 63;
  const int ch   = blockIdx.x >> 6;
  const int i0w  = ag * 64 + wid * 16;
  const int l15  = lane & 15;
  const int hi_l = lane >> 4;
  const int rbase = hi_l * 4;
  const int koff  = hi_l * 8;
  const int j0ch  = ch * 256;

  sJlab[tid] = labels[j0ch + tid];

  const int sj = (tid >> 2) & 15;
  const int sh = tid & 3;
  const int lofs = ((wid * 4 + sh) * 16 + sj) * 8;
  const int gofs = sj * DD + wid * 32 + sh * 8;

  short8 Ah[4], Al[4], Th[4], Tl[4];
  {
    const size_t ab = (size_t)(i0w + l15) * DD + koff;
#pragma unroll
    for (int s = 0; s < 4; ++s) {
      Ah[s] = *reinterpret_cast<const short8*>(xh + ab + s * 32);
      Al[s] = *reinterpret_cast<const short8*>(xl + ab + s * 32);
      Th[s] = *reinterpret_cast<const short8*>(yh + ab + s * 32);
      Tl[s] = *reinterpret_cast<const short8*>(yl + ab + s * 32);
    }
  }
  int labA[4]; float mpA[4], mnA[4];
#pragma unroll
  for (int r = 0; r < 4; ++r) {
    const int i_r = i0w + rbase + r;
    labA[r] = labels[i_r];
    float a = INFINITY, b = -INFINITY;
#pragma unroll 1
    for (int c = 0; c < NCH; ++c) {
      a = fminf(a, mpP[c * BB + i_r]);
      b = fmaxf(b, mnP[c * BB + i_r]);
    }
    mpA[r] = a; mnA[r] = b;
  }

  float zt[4], wv[4], ps[4], ns[4];
#pragma unroll
  for (int r = 0; r < 4; ++r) { zt[r] = 0.f; wv[r] = 0.f; ps[r] = 0.f; ns[r] = 0.f; }

  short8 stg[4];
#pragma unroll
  for (int k = 0; k < 4; ++k) {
    const unsigned short* base = (k & 2) ? ((k & 1) ? yl : yh)
                                         : ((k & 1) ? xl : xh);
    stg[k] = *reinterpret_cast<const short8*>(base + (size_t)j0ch * DD + gofs);
  }
#pragma unroll
  for (int k = 0; k < 4; ++k)
    *reinterpret_cast<short8*>(&sB[0][k * 2048 + lofs]) = stg[k];

#pragma unroll 1
  for (int pp = 0; pp < NP; ++pp) {
    const int cur = pp & 1;
    if (pp + 1 < NP) {
      const size_t gb = (size_t)(j0ch + (pp + 1) * 16) * DD + gofs;
#pragma unroll
      for (int k = 0; k < 4; ++k) {
        const unsigned short* base = (k & 2) ? ((k & 1) ? yl : yh)
                                             : ((k & 1) ? xl : xh);
        stg[k] = *reinterpret_cast<const short8*>(base + gb);
      }
    }
    __syncthreads();

    f32x4 aS = {0.f, 0.f, 0.f, 0.f}, aT = {0.f, 0.f, 0.f, 0.f};
#pragma unroll
    for (int s = 0; s < 4; ++s) {
      const int ro = ((s * 4 + hi_l) * 16 + l15) * 8;
      short8 vBh = *reinterpret_cast<const short8*>(&sB[cur][0 * 2048 + ro]);
      short8 vBl = *reinterpret_cast<const short8*>(&sB[cur][1 * 2048 + ro]);
      short8 vUh = *reinterpret_cast<const short8*>(&sB[cur][2 * 2048 + ro]);
      short8 vUl = *reinterpret_cast<const short8*>(&sB[cur][3 * 2048 + ro]);
      aS = mfma16(Ah[s], vBh, aS);
      aT = mfma16(Th[s], vUh, aT);
      aS = mfma16(Al[s], vBh, aS);
      aT = mfma16(Tl[s], vUh, aT);
      aS = mfma16(Ah[s], vBl, aS);
      aT = mfma16(Th[s], vUl, aT);
    }

    const int lj   = sJlab[pp * 16 + l15];
    const int jcol = j0ch + pp * 16 + l15;
#pragma unroll
    for (int r = 0; r < 4; ++r) {
      float sim = aS[r], ts0 = aT[r];
      bool same = (lj == labA[r]);
      float sc = same ? 0.25f : 0.125f;
      float s  = sim * sc;
      float ts = ts0 * sc;
      float et = __expf(ts);
      zt[r] += et;
      wv[r] += et * (ts - s);
      if (same) {
        if (jcol != i0w + rbase + r && (sim - MARGIN < mnA[r]))
          ps[r] += __expf(-POS_W * (sim - THRESH));
      } else {
        if (sim + MARGIN > mpA[r])
          ns[r] += __expf(NEG_W * (sim - THRESH));
      }
    }

    if (pp + 1 < NP) {
#pragma unroll
      for (int k = 0; k < 4; ++k)
        *reinterpret_cast<short8*>(&sB[cur ^ 1][k * 2048 + lofs]) = stg[k];
    }
  }

#pragma unroll
  for (int r = 0; r < 4; ++r)
#pragma unroll
    for (int m = 1; m < 16; m <<= 1) {
      zt[r] += __shfl_xor(zt[r], m);
      wv[r] += __shfl_xor(wv[r], m);
      ps[r] += __shfl_xor(ps[r], m);
      ns[r] += __shfl_xor(ns[r], m);
    }
  if (l15 == 0) {
#pragma unroll
    for (int r = 0; r < 4; ++r) {
      const int i_r = i0w + rbase + r;
      ztP[ch * BB + i_r] = zt[r];
      wvP[ch * BB + i_r] = wv[r];
      psP[ch * BB + i_r] = ps[r];
      nsP[ch * BB + i_r] = ns[r];
    }
  }
}

// ============ kD: per-anchor finalize, per-block partial ===================
__global__ __launch_bounds__(512) void kD(
    const float* __restrict__ zsP, const float* __restrict__ ztP,
    const float* __restrict__ wvP, const float* __restrict__ psP,
    const float* __restrict__ nsP,
    double* __restrict__ rkP, double* __restrict__ kdP, int* __restrict__ nvP)
{
  __shared__ double sR[8], sK[8];
  __shared__ int    sN[8];
  const int tid = threadIdx.x;
  const int lane = tid & 63;
  const int wid = tid >> 6;
  const int i = blockIdx.x * 512 + tid;

  float zs = 0.f, zt = 0.f, wv = 0.f, ps = 0.f, ns = 0.f;
#pragma unroll 1
  for (int c = 0; c < NCH; ++c) {
    zs += zsP[c * BB + i];
    zt += ztP[c * BB + i];
    wv += wvP[c * BB + i];
    ps += psP[c * BB + i];
    ns += nsP[c * BB + i];
  }
  double kd = (double)(wv / zt + __logf(zs) - __logf(zt));
  double rank = 0.0; int nv = 0;
  if (ps > 0.f && ns > 0.f) {
    rank = (double)(log1pf(ps) * 0.5f + log1pf(ns) * 0.025f);
    nv = 1;
  }
#pragma unroll
  for (int o = 32; o; o >>= 1) {
    rank += __shfl_xor(rank, o);
    kd   += __shfl_xor(kd, o);
    nv   += __shfl_xor(nv, o);
  }
  if (lane == 0) { sR[wid] = rank; sK[wid] = kd; sN[wid] = nv; }
  __syncthreads();
  if (tid == 0) {
    double R_ = 0.0, K_ = 0.0; int N_ = 0;
    for (int w = 0; w < 8; ++w) { R_ += sR[w]; K_ += sK[w]; N_ += sN[w]; }
    rkP[blockIdx.x] = R_;
    kdP[blockIdx.x] = K_;
    nvP[blockIdx.x] = N_;
  }
}

// ============ kE: merge 8 block partials -> outputs ========================
__global__ void kE(const double* __restrict__ rkP, const double* __restrict__ kdP,
                   const int* __restrict__ nvP, const int* __restrict__ epoch,
                   float* __restrict__ out)
{
  double R_ = 0.0, K_ = 0.0; int N_ = 0;
  for (int b = 0; b < 8; ++b) { R_ += rkP[b]; K_ += kdP[b]; N_ += nvP[b]; }
  double loss_rank = R_ / (double)(N_ < 1 ? 1 : N_);
  double loss_kd   = K_ / (double)BB;
  double wgt = (double)epoch[0] * 0.16;   // epoch/100 * ALPHA * TAU^2
  out[0] = (float)(loss_rank + wgt * loss_kd);
  out[1] = (float)loss_rank;
  out[2] = (float)loss_kd;
}

extern "C" void kernel_launch(void* const* d_in, const int* in_sizes, int n_in,
                              void* d_out, int out_size, void* d_ws, size_t ws_size,
                              hipStream_t stream)
{
  (void)in_sizes; (void)n_in; (void)out_size; (void)ws_size;
  const float* batch   = (const float*)d_in[0];
  const float* teacher = (const float*)d_in[1];
  const int*   labels  = (const int*)d_in[2];
  const int*   epoch   = (const int*)d_in[3];
  float* out = (float*)d_out;

  char* w = (char*)d_ws;
  const size_t MB = 1048576;
  unsigned short* bh = (unsigned short*)(w + 0 * MB);
  unsigned short* bl = (unsigned short*)(w + 1 * MB);
  unsigned short* th = (unsigned short*)(w + 2 * MB);
  unsigned short* tl = (unsigned short*)(w + 3 * MB);
  const size_t PCH = (size_t)NCH * BB * sizeof(float);   // 256 KB
  float* mpP = (float*)(w + 4 * MB);
  float* mnP = (float*)(w + 4 * MB + 1 * PCH);
  float* zsP = (float*)(w + 4 * MB + 2 * PCH);
  float* ztP = (float*)(w + 4 * MB + 3 * PCH);
  float* wvP = (float*)(w + 4 * MB + 4 * PCH);
  float* psP = (float*)(w + 4 * MB + 5 * PCH);
  float* nsP = (float*)(w + 4 * MB + 6 * PCH);
  double* rkP = (double*)(w + 6 * MB);
  double* kdP = (double*)(w + 6 * MB + 64);
  int*    nvP = (int*)(w + 6 * MB + 128);

  k0<<<dim3(BB * DD / 4 / 256), dim3(256), 0, stream>>>(batch, teacher, bh, bl, th, tl);
  kA<<<dim3(64 * NCH), dim3(TB), 0, stream>>>(bh, bl, labels, mpP, mnP, zsP);
  kB<<<dim3(64 * NCH), dim3(TB), 0, stream>>>(bh, bl, th, tl, labels, mpP, mnP,
                                              ztP, wvP, psP, nsP);
  kD<<<dim3(8), dim3(512), 0, stream>>>(zsP, ztP, wvP, psP, nsP, rkP, kdP, nvP);
  kE<<<dim3(1), dim3(1), 0, stream>>>(rkP, kdP, nvP, epoch, out);
}

// Round 8
// 86.421 us; speedup vs baseline: 14.4850x; 1.1370x over previous
//
#include <hip/hip_runtime.h>
#include <math.h>

#define BB  4096
#define DD  128
#define NCH 16             // j-chunks
#define NP  16             // panels per chunk
#define TB  256            // threads per block (4 waves)

typedef __attribute__((ext_vector_type(8))) short short8;
typedef __attribute__((ext_vector_type(4))) float f32x4;

constexpr float POS_W  = 2.0f;
constexpr float NEG_W  = 40.0f;
constexpr float MARGIN = 0.1f;
constexpr float THRESH = 0.5f;

__device__ __forceinline__ unsigned short f2bf(float f) {
  unsigned int u = __float_as_uint(f);
  return (unsigned short)((u + 0x7fffu + ((u >> 16) & 1u)) >> 16);
}
__device__ __forceinline__ float bf2f(unsigned short h) {
  return __uint_as_float(((unsigned int)h) << 16);
}
__device__ __forceinline__ f32x4 mfma16(short8 a, short8 b, f32x4 c) {
  return __builtin_amdgcn_mfma_f32_16x16x32_bf16(a, b, c, 0, 0, 0);
}
// async global->LDS, 16B per lane; lds dest = uniform base + lane*16
__device__ __forceinline__ void gll16(const void* g, void* l) {
  __builtin_amdgcn_global_load_lds(
      (const __attribute__((address_space(1))) void*)g,
      (__attribute__((address_space(3))) void*)l, 16, 0, 0);
}

// ============ k0: fp32 -> bf16 hi/lo split =================================
__global__ __launch_bounds__(256) void k0(
    const float* __restrict__ b, const float* __restrict__ t,
    unsigned short* __restrict__ bh, unsigned short* __restrict__ bl,
    unsigned short* __restrict__ th, unsigned short* __restrict__ tl)
{
  const int i = blockIdx.x * 256 + threadIdx.x;   // < BB*DD/4 = 131072
  {
    float4 v = reinterpret_cast<const float4*>(b)[i];
    ushort4 h, l;
    h.x = f2bf(v.x); l.x = f2bf(v.x - bf2f(h.x));
    h.y = f2bf(v.y); l.y = f2bf(v.y - bf2f(h.y));
    h.z = f2bf(v.z); l.z = f2bf(v.z - bf2f(h.z));
    h.w = f2bf(v.w); l.w = f2bf(v.w - bf2f(h.w));
    reinterpret_cast<ushort4*>(bh)[i] = h;
    reinterpret_cast<ushort4*>(bl)[i] = l;
  }
  {
    float4 v = reinterpret_cast<const float4*>(t)[i];
    ushort4 h, l;
    h.x = f2bf(v.x); l.x = f2bf(v.x - bf2f(h.x));
    h.y = f2bf(v.y); l.y = f2bf(v.y - bf2f(h.y));
    h.z = f2bf(v.z); l.z = f2bf(v.z - bf2f(h.z));
    h.w = f2bf(v.w); l.w = f2bf(v.w - bf2f(h.w));
    reinterpret_cast<ushort4*>(th)[i] = h;
    reinterpret_cast<ushort4*>(tl)[i] = l;
  }
}

// ============ kA: batch Gram chunk -> mp/mn/zs partials ====================
// LDS quad layout per array: q = (S*4+H)*16 + J  <->  row J, k in [S*32+H*8,+8)
// stage lane = H*16+J  ->  dest byte = wid*1024 + lane*16  (linear, uniform base)
__global__ __launch_bounds__(TB, 4) void kA(
    const unsigned short* __restrict__ xh,
    const unsigned short* __restrict__ xl,
    const int* __restrict__ labels,
    float* __restrict__ mpP, float* __restrict__ mnP, float* __restrict__ zsP)
{
  __shared__ unsigned short sB[2][2 * 2048];   // 16 KB
  __shared__ int sJlab[256];

  const int tid  = threadIdx.x;
  const int lane = tid & 63;
  const int wid  = tid >> 6;
  const int ag   = blockIdx.x & 63;
  const int ch   = blockIdx.x >> 6;
  const int i0w  = ag * 64 + wid * 16;
  const int l15  = lane & 15;
  const int hi_l = lane >> 4;
  const int rbase = hi_l * 4;
  const int koff  = hi_l * 8;
  const int j0ch  = ch * 256;
  const int gstg  = wid * 32 + (lane >> 4) * 8;   // per-lane k-offset for staging

  sJlab[tid] = labels[j0ch + tid];

  short8 Ah[4], Al[4];
  {
    const size_t ab = (size_t)(i0w + l15) * DD + koff;
#pragma unroll
    for (int s = 0; s < 4; ++s) {
      Ah[s] = *reinterpret_cast<const short8*>(xh + ab + s * 32);
      Al[s] = *reinterpret_cast<const short8*>(xl + ab + s * 32);
    }
  }
  int labA[4];
#pragma unroll
  for (int r = 0; r < 4; ++r) labA[r] = labels[i0w + rbase + r];

  float mp[4], mn[4], zs[4];
#pragma unroll
  for (int r = 0; r < 4; ++r) { mp[r] = INFINITY; mn[r] = -INFINITY; zs[r] = 0.f; }

  { // prologue stage: panel 0 -> buf 0
    const size_t go = (size_t)(j0ch + l15) * DD + gstg;
    gll16(xh + go, &sB[0][0 * 2048 + wid * 512]);
    gll16(xl + go, &sB[0][1 * 2048 + wid * 512]);
  }

#pragma unroll 1
  for (int pp = 0; pp < NP; ++pp) {
    const int cur = pp & 1;
    __syncthreads();                      // drains stage of buf[cur]
    if (pp + 1 < NP) {                    // issue next-panel loads; fly under compute
      const size_t go = (size_t)(j0ch + (pp + 1) * 16 + l15) * DD + gstg;
      gll16(xh + go, &sB[cur ^ 1][0 * 2048 + wid * 512]);
      gll16(xl + go, &sB[cur ^ 1][1 * 2048 + wid * 512]);
    }

    f32x4 acc = {0.f, 0.f, 0.f, 0.f};
#pragma unroll
    for (int s = 0; s < 4; ++s) {
      const int ro = ((s * 4 + hi_l) * 16 + l15) * 8;
      short8 vh = *reinterpret_cast<const short8*>(&sB[cur][ro]);
      short8 vl = *reinterpret_cast<const short8*>(&sB[cur][2048 + ro]);
      acc = mfma16(Ah[s], vh, acc);
      acc = mfma16(Al[s], vh, acc);
      acc = mfma16(Ah[s], vl, acc);
    }

    const int lj   = sJlab[pp * 16 + l15];
    const int jcol = j0ch + pp * 16 + l15;
#pragma unroll
    for (int r = 0; r < 4; ++r) {
      float sim = acc[r];
      bool same = (lj == labA[r]);
      zs[r] += __expf(sim * (same ? 0.25f : 0.125f));
      if (same) {
        if (jcol != i0w + rbase + r) mp[r] = fminf(mp[r], sim);
      } else {
        mn[r] = fmaxf(mn[r], sim);
      }
    }
  }

#pragma unroll
  for (int r = 0; r < 4; ++r)
#pragma unroll
    for (int m = 1; m < 16; m <<= 1) {
      mp[r] = fminf(mp[r], __shfl_xor(mp[r], m));
      mn[r] = fmaxf(mn[r], __shfl_xor(mn[r], m));
      zs[r] += __shfl_xor(zs[r], m);
    }
  if (l15 == 0) {
#pragma unroll
    for (int r = 0; r < 4; ++r) {
      const int i_r = i0w + rbase + r;
      mpP[ch * BB + i_r] = mp[r];
      mnP[ch * BB + i_r] = mn[r];
      zsP[ch * BB + i_r] = zs[r];
    }
  }
}

// ============ kR: merge chunk partials -> per-row stats ====================
__global__ __launch_bounds__(256) void kR(
    const float* __restrict__ mpP, const float* __restrict__ mnP,
    const float* __restrict__ zsP,
    float* __restrict__ mpg, float* __restrict__ mng, float* __restrict__ zsg)
{
  const int i = blockIdx.x * 256 + threadIdx.x;
  float a = INFINITY, b = -INFINITY, c = 0.f;
#pragma unroll
  for (int ch = 0; ch < NCH; ++ch) {
    a = fminf(a, mpP[ch * BB + i]);
    b = fmaxf(b, mnP[ch * BB + i]);
    c += zsP[ch * BB + i];
  }
  mpg[i] = a; mng[i] = b; zsg[i] = c;
}

// ============ kB: batch+teacher Gram chunk -> zt/wv/ps/ns partials =========
__global__ __launch_bounds__(TB, 4) void kB(
    const unsigned short* __restrict__ xh, const unsigned short* __restrict__ xl,
    const unsigned short* __restrict__ yh, const unsigned short* __restrict__ yl,
    const int* __restrict__ labels,
    const float* __restrict__ mpg, const float* __restrict__ mng,
    float* __restrict__ ztP, float* __restrict__ wvP,
    float* __restrict__ psP, float* __restrict__ nsP)
{
  __shared__ unsigned short sB[2][4 * 2048];   // 32 KB
  __shared__ int sJlab[256];

  const int tid  = threadIdx.x;
  const int lane = tid & 63;
  const int wid  = tid >> 6;
  const int ag   = blockIdx.x & 63;
  const int ch   = blockIdx.x >> 6;
  const int i0w  = ag * 64 + wid * 16;
  const int l15  = lane & 15;
  const int hi_l = lane >> 4;
  const int rbase = hi_l * 4;
  const int koff  = hi_l * 8;
  const int j0ch  = ch * 256;
  const int gstg  = wid * 32 + (lane >> 4) * 8;

  sJlab[tid] = labels[j0ch + tid];

  short8 Ah[4], Al[4], Th[4], Tl[4];
  {
    const size_t ab = (size_t)(i0w + l15) * DD + koff;
#pragma unroll
    for (int s = 0; s < 4; ++s) {
      Ah[s] = *reinterpret_cast<const short8*>(xh + ab + s * 32);
      Al[s] = *reinterpret_cast<const short8*>(xl + ab + s * 32);
      Th[s] = *reinterpret_cast<const short8*>(yh + ab + s * 32);
      Tl[s] = *reinterpret_cast<const short8*>(yl + ab + s * 32);
    }
  }
  int labA[4]; float mpA[4], mnA[4];
#pragma unroll
  for (int r = 0; r < 4; ++r) {
    const int i_r = i0w + rbase + r;
    labA[r] = labels[i_r];
    mpA[r]  = mpg[i_r];
    mnA[r]  = mng[i_r];
  }

  float zt[4], wv[4], ps[4], ns[4];
#pragma unroll
  for (int r = 0; r < 4; ++r) { zt[r] = 0.f; wv[r] = 0.f; ps[r] = 0.f; ns[r] = 0.f; }

  { // prologue stage: panel 0 -> buf 0 (4 arrays)
    const size_t go = (size_t)(j0ch + l15) * DD + gstg;
    gll16(xh + go, &sB[0][0 * 2048 + wid * 512]);
    gll16(xl + go, &sB[0][1 * 2048 + wid * 512]);
    gll16(yh + go, &sB[0][2 * 2048 + wid * 512]);
    gll16(yl + go, &sB[0][3 * 2048 + wid * 512]);
  }

#pragma unroll 1
  for (int pp = 0; pp < NP; ++pp) {
    const int cur = pp & 1;
    __syncthreads();
    if (pp + 1 < NP) {
      const size_t go = (size_t)(j0ch + (pp + 1) * 16 + l15) * DD + gstg;
      gll16(xh + go, &sB[cur ^ 1][0 * 2048 + wid * 512]);
      gll16(xl + go, &sB[cur ^ 1][1 * 2048 + wid * 512]);
      gll16(yh + go, &sB[cur ^ 1][2 * 2048 + wid * 512]);
      gll16(yl + go, &sB[cur ^ 1][3 * 2048 + wid * 512]);
    }

    f32x4 aS = {0.f, 0.f, 0.f, 0.f}, aT = {0.f, 0.f, 0.f, 0.f};
#pragma unroll
    for (int s = 0; s < 4; ++s) {
      const int ro = ((s * 4 + hi_l) * 16 + l15) * 8;
      short8 vBh = *reinterpret_cast<const short8*>(&sB[cur][0 * 2048 + ro]);
      short8 vBl = *reinterpret_cast<const short8*>(&sB[cur][1 * 2048 + ro]);
      short8 vUh = *reinterpret_cast<const short8*>(&sB[cur][2 * 2048 + ro]);
      short8 vUl = *reinterpret_cast<const short8*>(&sB[cur][3 * 2048 + ro]);
      aS = mfma16(Ah[s], vBh, aS);
      aT = mfma16(Th[s], vUh, aT);
      aS = mfma16(Al[s], vBh, aS);
      aT = mfma16(Tl[s], vUh, aT);
      aS = mfma16(Ah[s], vBl, aS);
      aT = mfma16(Th[s], vUl, aT);
    }

    const int lj   = sJlab[pp * 16 + l15];
    const int jcol = j0ch + pp * 16 + l15;
#pragma unroll
    for (int r = 0; r < 4; ++r) {
      float sim = aS[r], ts0 = aT[r];
      bool same = (lj == labA[r]);
      float sc = same ? 0.25f : 0.125f;
      float s  = sim * sc;
      float ts = ts0 * sc;
      float et = __expf(ts);
      zt[r] += et;
      wv[r] += et * (ts - s);
      if (same) {
        if (jcol != i0w + rbase + r && (sim - MARGIN < mnA[r]))
          ps[r] += __expf(-POS_W * (sim - THRESH));
      } else {
        if (sim + MARGIN > mpA[r])
          ns[r] += __expf(NEG_W * (sim - THRESH));
      }
    }
  }

#pragma unroll
  for (int r = 0; r < 4; ++r)
#pragma unroll
    for (int m = 1; m < 16; m <<= 1) {
      zt[r] += __shfl_xor(zt[r], m);
      wv[r] += __shfl_xor(wv[r], m);
      ps[r] += __shfl_xor(ps[r], m);
      ns[r] += __shfl_xor(ns[r], m);
    }
  if (l15 == 0) {
#pragma unroll
    for (int r = 0; r < 4; ++r) {
      const int i_r = i0w + rbase + r;
      ztP[ch * BB + i_r] = zt[r];
      wvP[ch * BB + i_r] = wv[r];
      psP[ch * BB + i_r] = ps[r];
      nsP[ch * BB + i_r] = ns[r];
    }
  }
}

// ============ kD: per-anchor finalize, per-block partial ===================
__global__ __launch_bounds__(512) void kD(
    const float* __restrict__ zsg, const float* __restrict__ ztP,
    const float* __restrict__ wvP, const float* __restrict__ psP,
    const float* __restrict__ nsP,
    double* __restrict__ rkP, double* __restrict__ kdP, int* __restrict__ nvP)
{
  __shared__ double sR[8], sK[8];
  __shared__ int    sN[8];
  const int tid = threadIdx.x;
  const int lane = tid & 63;
  const int wid = tid >> 6;
  const int i = blockIdx.x * 512 + tid;

  float zt = 0.f, wv = 0.f, ps = 0.f, ns = 0.f;
#pragma unroll
  for (int c = 0; c < NCH; ++c) {
    zt += ztP[c * BB + i];
    wv += wvP[c * BB + i];
    ps += psP[c * BB + i];
    ns += nsP[c * BB + i];
  }
  float zs = zsg[i];
  double kd = (double)(wv / zt + __logf(zs) - __logf(zt));
  double rank = 0.0; int nv = 0;
  if (ps > 0.f && ns > 0.f) {
    rank = (double)(log1pf(ps) * 0.5f + log1pf(ns) * 0.025f);
    nv = 1;
  }
#pragma unroll
  for (int o = 32; o; o >>= 1) {
    rank += __shfl_xor(rank, o);
    kd   += __shfl_xor(kd, o);
    nv   += __shfl_xor(nv, o);
  }
  if (lane == 0) { sR[wid] = rank; sK[wid] = kd; sN[wid] = nv; }
  __syncthreads();
  if (tid == 0) {
    double R_ = 0.0, K_ = 0.0; int N_ = 0;
    for (int w = 0; w < 8; ++w) { R_ += sR[w]; K_ += sK[w]; N_ += sN[w]; }
    rkP[blockIdx.x] = R_;
    kdP[blockIdx.x] = K_;
    nvP[blockIdx.x] = N_;
  }
}

// ============ kE: merge 8 block partials -> outputs ========================
__global__ void kE(const double* __restrict__ rkP, const double* __restrict__ kdP,
                   const int* __restrict__ nvP, const int* __restrict__ epoch,
                   float* __restrict__ out)
{
  double R_ = 0.0, K_ = 0.0; int N_ = 0;
  for (int b = 0; b < 8; ++b) { R_ += rkP[b]; K_ += kdP[b]; N_ += nvP[b]; }
  double loss_rank = R_ / (double)(N_ < 1 ? 1 : N_);
  double loss_kd   = K_ / (double)BB;
  double wgt = (double)epoch[0] * 0.16;   // epoch/100 * ALPHA * TAU^2
  out[0] = (float)(loss_rank + wgt * loss_kd);
  out[1] = (float)loss_rank;
  out[2] = (float)loss_kd;
}

extern "C" void kernel_launch(void* const* d_in, const int* in_sizes, int n_in,
                              void* d_out, int out_size, void* d_ws, size_t ws_size,
                              hipStream_t stream)
{
  (void)in_sizes; (void)n_in; (void)out_size; (void)ws_size;
  const float* batch   = (const float*)d_in[0];
  const float* teacher = (const float*)d_in[1];
  const int*   labels  = (const int*)d_in[2];
  const int*   epoch   = (const int*)d_in[3];
  float* out = (float*)d_out;

  char* w = (char*)d_ws;
  const size_t MB = 1048576;
  unsigned short* bh = (unsigned short*)(w + 0 * MB);
  unsigned short* bl = (unsigned short*)(w + 1 * MB);
  unsigned short* th = (unsigned short*)(w + 2 * MB);
  unsigned short* tl = (unsigned short*)(w + 3 * MB);
  const size_t PCH = (size_t)NCH * BB * sizeof(float);   // 256 KB
  float* mpP = (float*)(w + 4 * MB + 0 * PCH);
  float* mnP = (float*)(w + 4 * MB + 1 * PCH);
  float* zsP = (float*)(w + 4 * MB + 2 * PCH);
  float* ztP = (float*)(w + 4 * MB + 3 * PCH);
  float* wvP = (float*)(w + 4 * MB + 4 * PCH);
  float* psP = (float*)(w + 4 * MB + 5 * PCH);
  float* nsP = (float*)(w + 4 * MB + 6 * PCH);
  float* mpg = (float*)(w + 6 * MB);
  float* mng = (float*)(w + 6 * MB + 16384);
  float* zsg = (float*)(w + 6 * MB + 32768);
  double* rkP = (double*)(w + 6 * MB + 49152);
  double* kdP = (double*)(w + 6 * MB + 49152 + 64);
  int*    nvP = (int*)(w + 6 * MB + 49152 + 128);

  k0<<<dim3(BB * DD / 4 / 256), dim3(256), 0, stream>>>(batch, teacher, bh, bl, th, tl);
  kA<<<dim3(64 * NCH), dim3(TB), 0, stream>>>(bh, bl, labels, mpP, mnP, zsP);
  kR<<<dim3(BB / 256), dim3(256), 0, stream>>>(mpP, mnP, zsP, mpg, mng, zsg);
  kB<<<dim3(64 * NCH), dim3(TB), 0, stream>>>(bh, bl, th, tl, labels, mpg, mng,
                                              ztP, wvP, psP, nsP);
  kD<<<dim3(8), dim3(512), 0, stream>>>(zsg, ztP, wvP, psP, nsP, rkP, kdP, nvP);
  kE<<<dim3(1), dim3(1), 0, stream>>>(rkP, kdP, nvP, epoch, out);
}

// Round 10
// 68.521 us; speedup vs baseline: 18.2692x; 1.2612x over previous
//
#include <hip/hip_runtime.h>
#include <hip/hip_fp16.h>
#include <math.h>

#define BB  4096
#define DD  128
#define NCH 16             // j-chunks (256 j each)
#define NP  16             // panels per chunk (16 j each)
#define TB  256            // threads per block (4 waves)

typedef __attribute__((ext_vector_type(8))) _Float16 half8;
typedef __attribute__((ext_vector_type(4))) float f32x4;

constexpr float POS_W  = 2.0f;
constexpr float NEG_W  = 40.0f;
constexpr float MARGIN = 0.1f;
constexpr float THRESH = 0.5f;

__device__ __forceinline__ unsigned short f2h(float f) {
  __half h = __float2half(f);
  return __half_as_ushort(h);
}
__device__ __forceinline__ f32x4 mfma16h(half8 a, half8 b, f32x4 c) {
  return __builtin_amdgcn_mfma_f32_16x16x32_f16(a, b, c, 0, 0, 0);
}
// async global->LDS, 16B per lane; lds dest = uniform base + lane*16
__device__ __forceinline__ void gll16(const void* g, void* l) {
  __builtin_amdgcn_global_load_lds(
      (const __attribute__((address_space(1))) void*)g,
      (__attribute__((address_space(3))) void*)l, 16, 0, 0);
}

// ============ k0: fp32 -> fp16 for batch & teacher =========================
__global__ __launch_bounds__(256) void k0(
    const float* __restrict__ b, const float* __restrict__ t,
    unsigned short* __restrict__ xf, unsigned short* __restrict__ yf)
{
  const int i = blockIdx.x * 256 + threadIdx.x;   // < BB*DD/4 = 131072
  {
    float4 v = reinterpret_cast<const float4*>(b)[i];
    ushort4 h;
    h.x = f2h(v.x); h.y = f2h(v.y); h.z = f2h(v.z); h.w = f2h(v.w);
    reinterpret_cast<ushort4*>(xf)[i] = h;
  }
  {
    float4 v = reinterpret_cast<const float4*>(t)[i];
    ushort4 h;
    h.x = f2h(v.x); h.y = f2h(v.y); h.z = f2h(v.z); h.w = f2h(v.w);
    reinterpret_cast<ushort4*>(yf)[i] = h;
  }
}

// ============ kA: batch Gram chunk -> mp/mn/zs partials ====================
// block = 128 anchors (4 waves x 32), chunk of 16 panels (256 j).
// LDS frag order: elem q*8, q=(S*4+H)*16+J  <->  row J, k in [S*32+H*8,+8)
// stage: lane=H*16+J -> dest byte = wid*1024 + lane*16 (linear, uniform base)
__global__ __launch_bounds__(TB, 4) void kA(
    const unsigned short* __restrict__ xf,
    const int* __restrict__ labels,
    float* __restrict__ mpP, float* __restrict__ mnP, float* __restrict__ zsP)
{
  __shared__ unsigned short sX[2][2048];   // 8 KB
  __shared__ int sJlab[256];

  const int tid  = threadIdx.x;
  const int lane = tid & 63;
  const int wid  = tid >> 6;
  const int ag   = blockIdx.x & 31;
  const int ch   = blockIdx.x >> 5;
  const int i0w  = ag * 128 + wid * 32;
  const int l15  = lane & 15;
  const int hi_l = lane >> 4;
  const int rbase = hi_l * 4;
  const int koff  = hi_l * 8;
  const int j0ch  = ch * 256;
  const int gstg  = wid * 32 + hi_l * 8;

  sJlab[tid] = labels[j0ch + tid];

  half8 Ax[2][4];
#pragma unroll
  for (int at = 0; at < 2; ++at) {
    const size_t ab = (size_t)(i0w + at * 16 + l15) * DD + koff;
#pragma unroll
    for (int s = 0; s < 4; ++s)
      Ax[at][s] = *reinterpret_cast<const half8*>(xf + ab + s * 32);
  }
  int labA[2][4];
#pragma unroll
  for (int at = 0; at < 2; ++at)
#pragma unroll
    for (int r = 0; r < 4; ++r) labA[at][r] = labels[i0w + at * 16 + rbase + r];

  float mp[2][4], mn[2][4], zs[2][4];
#pragma unroll
  for (int at = 0; at < 2; ++at)
#pragma unroll
    for (int r = 0; r < 4; ++r) { mp[at][r] = INFINITY; mn[at][r] = -INFINITY; zs[at][r] = 0.f; }

  { // prologue stage: panel 0 -> buf 0
    const size_t go = (size_t)(j0ch + l15) * DD + gstg;
    gll16(xf + go, &sX[0][wid * 512]);
  }

#pragma unroll 1
  for (int pp = 0; pp < NP; ++pp) {
    const int cur = pp & 1;
    __syncthreads();
    if (pp + 1 < NP) {
      const size_t go = (size_t)(j0ch + (pp + 1) * 16 + l15) * DD + gstg;
      gll16(xf + go, &sX[cur ^ 1][wid * 512]);
    }

    f32x4 a0 = {0.f, 0.f, 0.f, 0.f}, a1 = {0.f, 0.f, 0.f, 0.f};
#pragma unroll
    for (int s = 0; s < 4; ++s) {
      const int ro = ((s * 4 + hi_l) * 16 + l15) * 8;
      half8 vB = *reinterpret_cast<const half8*>(&sX[cur][ro]);
      a0 = mfma16h(Ax[0][s], vB, a0);
      a1 = mfma16h(Ax[1][s], vB, a1);
    }

    const int lj   = sJlab[pp * 16 + l15];
    const int jcol = j0ch + pp * 16 + l15;
#pragma unroll
    for (int at = 0; at < 2; ++at) {
      f32x4 acc = at ? a1 : a0;
#pragma unroll
      for (int r = 0; r < 4; ++r) {
        float sim = acc[r];
        bool same = (lj == labA[at][r]);
        zs[at][r] += __expf(sim * (same ? 0.25f : 0.125f));
        if (same) {
          if (jcol != i0w + at * 16 + rbase + r) mp[at][r] = fminf(mp[at][r], sim);
        } else {
          mn[at][r] = fmaxf(mn[at][r], sim);
        }
      }
    }
  }

#pragma unroll
  for (int at = 0; at < 2; ++at)
#pragma unroll
    for (int r = 0; r < 4; ++r)
#pragma unroll
      for (int m = 1; m < 16; m <<= 1) {
        mp[at][r] = fminf(mp[at][r], __shfl_xor(mp[at][r], m));
        mn[at][r] = fmaxf(mn[at][r], __shfl_xor(mn[at][r], m));
        zs[at][r] += __shfl_xor(zs[at][r], m);
      }
  if (l15 == 0) {
#pragma unroll
    for (int at = 0; at < 2; ++at)
#pragma unroll
      for (int r = 0; r < 4; ++r) {
        const int i_r = i0w + at * 16 + rbase + r;
        mpP[ch * BB + i_r] = mp[at][r];
        mnP[ch * BB + i_r] = mn[at][r];
        zsP[ch * BB + i_r] = zs[at][r];
      }
  }
}

// ============ kR: merge chunk partials -> per-row stats ====================
__global__ __launch_bounds__(256) void kR(
    const float* __restrict__ mpP, const float* __restrict__ mnP,
    const float* __restrict__ zsP,
    float* __restrict__ mpg, float* __restrict__ mng, float* __restrict__ zsg)
{
  const int i = blockIdx.x * 256 + threadIdx.x;
  float a = INFINITY, b = -INFINITY, c = 0.f;
#pragma unroll
  for (int ch = 0; ch < NCH; ++ch) {
    a = fminf(a, mpP[ch * BB + i]);
    b = fmaxf(b, mnP[ch * BB + i]);
    c += zsP[ch * BB + i];
  }
  mpg[i] = a; mng[i] = b; zsg[i] = c;
}

// ============ kB: batch+teacher Gram chunk -> zt/wv/ps/ns partials =========
__global__ __launch_bounds__(TB, 2) void kB(
    const unsigned short* __restrict__ xf, const unsigned short* __restrict__ yf,
    const int* __restrict__ labels,
    const float* __restrict__ mpg, const float* __restrict__ mng,
    float* __restrict__ ztP, float* __restrict__ wvP,
    float* __restrict__ psP, float* __restrict__ nsP)
{
  __shared__ unsigned short sB[2][2 * 2048];   // 16 KB: [buf][arr*2048 + q*8]
  __shared__ int sJlab[256];

  const int tid  = threadIdx.x;
  const int lane = tid & 63;
  const int wid  = tid >> 6;
  const int ag   = blockIdx.x & 31;
  const int ch   = blockIdx.x >> 5;
  const int i0w  = ag * 128 + wid * 32;
  const int l15  = lane & 15;
  const int hi_l = lane >> 4;
  const int rbase = hi_l * 4;
  const int koff  = hi_l * 8;
  const int j0ch  = ch * 256;
  const int gstg  = wid * 32 + hi_l * 8;

  sJlab[tid] = labels[j0ch + tid];

  half8 Ax[2][4], Ay[2][4];
#pragma unroll
  for (int at = 0; at < 2; ++at) {
    const size_t ab = (size_t)(i0w + at * 16 + l15) * DD + koff;
#pragma unroll
    for (int s = 0; s < 4; ++s) {
      Ax[at][s] = *reinterpret_cast<const half8*>(xf + ab + s * 32);
      Ay[at][s] = *reinterpret_cast<const half8*>(yf + ab + s * 32);
    }
  }
  int labA[2][4]; float mpA[2][4], mnA[2][4];
#pragma unroll
  for (int at = 0; at < 2; ++at)
#pragma unroll
    for (int r = 0; r < 4; ++r) {
      const int i_r = i0w + at * 16 + rbase + r;
      labA[at][r] = labels[i_r];
      mpA[at][r]  = mpg[i_r];
      mnA[at][r]  = mng[i_r];
    }

  float zt[2][4], wv[2][4], ps[2][4], ns[2][4];
#pragma unroll
  for (int at = 0; at < 2; ++at)
#pragma unroll
    for (int r = 0; r < 4; ++r) { zt[at][r] = 0.f; wv[at][r] = 0.f; ps[at][r] = 0.f; ns[at][r] = 0.f; }

  { // prologue stage: panel 0 -> buf 0 (x and y)
    const size_t go = (size_t)(j0ch + l15) * DD + gstg;
    gll16(xf + go, &sB[0][0 * 2048 + wid * 512]);
    gll16(yf + go, &sB[0][1 * 2048 + wid * 512]);
  }

#pragma unroll 1
  for (int pp = 0; pp < NP; ++pp) {
    const int cur = pp & 1;
    __syncthreads();
    if (pp + 1 < NP) {
      const size_t go = (size_t)(j0ch + (pp + 1) * 16 + l15) * DD + gstg;
      gll16(xf + go, &sB[cur ^ 1][0 * 2048 + wid * 512]);
      gll16(yf + go, &sB[cur ^ 1][1 * 2048 + wid * 512]);
    }

    f32x4 aS0 = {0.f,0.f,0.f,0.f}, aS1 = {0.f,0.f,0.f,0.f};
    f32x4 aT0 = {0.f,0.f,0.f,0.f}, aT1 = {0.f,0.f,0.f,0.f};
#pragma unroll
    for (int s = 0; s < 4; ++s) {
      const int ro = ((s * 4 + hi_l) * 16 + l15) * 8;
      half8 vX = *reinterpret_cast<const half8*>(&sB[cur][ro]);
      half8 vY = *reinterpret_cast<const half8*>(&sB[cur][2048 + ro]);
      aS0 = mfma16h(Ax[0][s], vX, aS0);
      aS1 = mfma16h(Ax[1][s], vX, aS1);
      aT0 = mfma16h(Ay[0][s], vY, aT0);
      aT1 = mfma16h(Ay[1][s], vY, aT1);
    }

    const int lj   = sJlab[pp * 16 + l15];
    const int jcol = j0ch + pp * 16 + l15;
#pragma unroll
    for (int at = 0; at < 2; ++at) {
      f32x4 aS = at ? aS1 : aS0;
      f32x4 aT = at ? aT1 : aT0;
#pragma unroll
      for (int r = 0; r < 4; ++r) {
        float sim = aS[r], ts0 = aT[r];
        bool same = (lj == labA[at][r]);
        float sc = same ? 0.25f : 0.125f;
        float s  = sim * sc;
        float ts = ts0 * sc;
        float et = __expf(ts);
        zt[at][r] += et;
        wv[at][r] += et * (ts - s);
        if (same) {
          if (jcol != i0w + at * 16 + rbase + r && (sim - MARGIN < mnA[at][r]))
            ps[at][r] += __expf(-POS_W * (sim - THRESH));
        } else {
          if (sim + MARGIN > mpA[at][r])
            ns[at][r] += __expf(NEG_W * (sim - THRESH));
        }
      }
    }
  }

#pragma unroll
  for (int at = 0; at < 2; ++at)
#pragma unroll
    for (int r = 0; r < 4; ++r)
#pragma unroll
      for (int m = 1; m < 16; m <<= 1) {
        zt[at][r] += __shfl_xor(zt[at][r], m);
        wv[at][r] += __shfl_xor(wv[at][r], m);
        ps[at][r] += __shfl_xor(ps[at][r], m);
        ns[at][r] += __shfl_xor(ns[at][r], m);
      }
  if (l15 == 0) {
#pragma unroll
    for (int at = 0; at < 2; ++at)
#pragma unroll
      for (int r = 0; r < 4; ++r) {
        const int i_r = i0w + at * 16 + rbase + r;
        ztP[ch * BB + i_r] = zt[at][r];
        wvP[ch * BB + i_r] = wv[at][r];
        psP[ch * BB + i_r] = ps[at][r];
        nsP[ch * BB + i_r] = ns[at][r];
      }
  }
}

// ============ kD: per-anchor finalize, per-block partial ===================
__global__ __launch_bounds__(512) void kD(
    const float* __restrict__ zsg, const float* __restrict__ ztP,
    const float* __restrict__ wvP, const float* __restrict__ psP,
    const float* __restrict__ nsP,
    double* __restrict__ rkP, double* __restrict__ kdP, int* __restrict__ nvP)
{
  __shared__ double sR[8], sK[8];
  __shared__ int    sN[8];
  const int tid = threadIdx.x;
  const int lane = tid & 63;
  const int wid = tid >> 6;
  const int i = blockIdx.x * 512 + tid;

  float zt = 0.f, wv = 0.f, ps = 0.f, ns = 0.f;
#pragma unroll
  for (int c = 0; c < NCH; ++c) {
    zt += ztP[c * BB + i];
    wv += wvP[c * BB + i];
    ps += psP[c * BB + i];
    ns += nsP[c * BB + i];
  }
  float zs = zsg[i];
  double kd = (double)(wv / zt + __logf(zs) - __logf(zt));
  double rank = 0.0; int nv = 0;
  if (ps > 0.f && ns > 0.f) {
    rank = (double)(log1pf(ps) * 0.5f + log1pf(ns) * 0.025f);
    nv = 1;
  }
#pragma unroll
  for (int o = 32; o; o >>= 1) {
    rank += __shfl_xor(rank, o);
    kd   += __shfl_xor(kd, o);
    nv   += __shfl_xor(nv, o);
  }
  if (lane == 0) { sR[wid] = rank; sK[wid] = kd; sN[wid] = nv; }
  __syncthreads();
  if (tid == 0) {
    double R_ = 0.0, K_ = 0.0; int N_ = 0;
    for (int w = 0; w < 8; ++w) { R_ += sR[w]; K_ += sK[w]; N_ += sN[w]; }
    rkP[blockIdx.x] = R_;
    kdP[blockIdx.x] = K_;
    nvP[blockIdx.x] = N_;
  }
}

// ============ kE: merge 8 block partials -> outputs ========================
__global__ void kE(const double* __restrict__ rkP, const double* __restrict__ kdP,
                   const int* __restrict__ nvP, const int* __restrict__ epoch,
                   float* __restrict__ out)
{
  double R_ = 0.0, K_ = 0.0; int N_ = 0;
  for (int b = 0; b < 8; ++b) { R_ += rkP[b]; K_ += kdP[b]; N_ += nvP[b]; }
  double loss_rank = R_ / (double)(N_ < 1 ? 1 : N_);
  double loss_kd   = K_ / (double)BB;
  double wgt = (double)epoch[0] * 0.16;   // epoch/100 * ALPHA * TAU^2
  out[0] = (float)(loss_rank + wgt * loss_kd);
  out[1] = (float)loss_rank;
  out[2] = (float)loss_kd;
}

extern "C" void kernel_launch(void* const* d_in, const int* in_sizes, int n_in,
                              void* d_out, int out_size, void* d_ws, size_t ws_size,
                              hipStream_t stream)
{
  (void)in_sizes; (void)n_in; (void)out_size; (void)ws_size;
  const float* batch   = (const float*)d_in[0];
  const float* teacher = (const float*)d_in[1];
  const int*   labels  = (const int*)d_in[2];
  const int*   epoch   = (const int*)d_in[3];
  float* out = (float*)d_out;

  char* w = (char*)d_ws;
  const size_t MB = 1048576;
  unsigned short* xf = (unsigned short*)(w + 0 * MB);   // 1 MB each
  unsigned short* yf = (unsigned short*)(w + 1 * MB);
  const size_t PCH = (size_t)NCH * BB * sizeof(float);  // 256 KB
  float* mpP = (float*)(w + 2 * MB + 0 * PCH);
  float* mnP = (float*)(w + 2 * MB + 1 * PCH);
  float* zsP = (float*)(w + 2 * MB + 2 * PCH);
  float* ztP = (float*)(w + 2 * MB + 3 * PCH);
  float* wvP = (float*)(w + 2 * MB + 4 * PCH);
  float* psP = (float*)(w + 2 * MB + 5 * PCH);
  float* nsP = (float*)(w + 2 * MB + 6 * PCH);
  float* mpg = (float*)(w + 4 * MB);
  float* mng = (float*)(w + 4 * MB + 16384);
  float* zsg = (float*)(w + 4 * MB + 32768);
  double* rkP = (double*)(w + 4 * MB + 49152);
  double* kdP = (double*)(w + 4 * MB + 49152 + 64);
  int*    nvP = (int*)(w + 4 * MB + 49152 + 128);

  k0<<<dim3(BB * DD / 4 / 256), dim3(256), 0, stream>>>(batch, teacher, xf, yf);
  kA<<<dim3(32 * NCH), dim3(TB), 0, stream>>>(xf, labels, mpP, mnP, zsP);
  kR<<<dim3(BB / 256), dim3(256), 0, stream>>>(mpP, mnP, zsP, mpg, mng, zsg);
  kB<<<dim3(32 * NCH), dim3(TB), 0, stream>>>(xf, yf, labels, mpg, mng,
                                              ztP, wvP, psP, nsP);
  kD<<<dim3(8), dim3(512), 0, stream>>>(zsg, ztP, wvP, psP, nsP, rkP, kdP, nvP);
  kE<<<dim3(1), dim3(1), 0, stream>>>(rkP, kdP, nvP, epoch, out);
}

// Round 11
// 63.482 us; speedup vs baseline: 19.7194x; 1.0794x over previous
//
#include <hip/hip_runtime.h>
#include <hip/hip_fp16.h>
#include <math.h>

#define BB  4096
#define DD  128
#define NCH 16             // j-chunks (256 j each)
#define NP  8              // panels per chunk (32 j each)
#define TB  256            // threads per block (4 waves)

typedef __attribute__((ext_vector_type(8))) _Float16 half8;
typedef __attribute__((ext_vector_type(4))) float f32x4;

constexpr float POS_W  = 2.0f;
constexpr float NEG_W  = 40.0f;
constexpr float MARGIN = 0.1f;
constexpr float THRESH = 0.5f;

__device__ __forceinline__ unsigned short f2h(float f) {
  __half h = __float2half(f);
  return __half_as_ushort(h);
}
__device__ __forceinline__ f32x4 mfma16h(half8 a, half8 b, f32x4 c) {
  return __builtin_amdgcn_mfma_f32_16x16x32_f16(a, b, c, 0, 0, 0);
}
// async global->LDS, 16B per lane; lds dest = uniform base + lane*16
__device__ __forceinline__ void gll16(const void* g, void* l) {
  __builtin_amdgcn_global_load_lds(
      (const __attribute__((address_space(1))) void*)g,
      (__attribute__((address_space(3))) void*)l, 16, 0, 0);
}

// ============ k0: fp32 -> fp16 for batch & teacher =========================
__global__ __launch_bounds__(256) void k0(
    const float* __restrict__ b, const float* __restrict__ t,
    unsigned short* __restrict__ xf, unsigned short* __restrict__ yf)
{
  const int i = blockIdx.x * 256 + threadIdx.x;   // < BB*DD/4 = 131072
  {
    float4 v = reinterpret_cast<const float4*>(b)[i];
    ushort4 h;
    h.x = f2h(v.x); h.y = f2h(v.y); h.z = f2h(v.z); h.w = f2h(v.w);
    reinterpret_cast<ushort4*>(xf)[i] = h;
  }
  {
    float4 v = reinterpret_cast<const float4*>(t)[i];
    ushort4 h;
    h.x = f2h(v.x); h.y = f2h(v.y); h.z = f2h(v.z); h.w = f2h(v.w);
    reinterpret_cast<ushort4*>(yf)[i] = h;
  }
}

// LDS panel layout (per array, 32-j panel, 8 KB = 512 slots of 16B):
//   slot = S*128 + H*32 + J   (S=k-step in [0,4), H=k-sub in [0,4), J=j in [0,32))
//   <-> row J, k in [S*32 + H*8, +8)
// staging: wave wid covers S=wid slice; shot s2 in {0,1}: 64 lanes write slots
//   wid*128 + s2*64 + lane  (lane-linear, uniform base ✓)
//   source row = j0p + (lane&31), k = wid*32 + (s2*2 + (lane>>5))*8
// fragment read (k-step s, j-tile t): slot = s*128 + hi_l*32 + t*16 + l15

// ============ kA: batch Gram chunk -> mp/mn/zs partials ====================
__global__ __launch_bounds__(TB, 3) void kA(
    const unsigned short* __restrict__ xf,
    const int* __restrict__ labels,
    float* __restrict__ mpP, float* __restrict__ mnP, float* __restrict__ zsP)
{
  __shared__ unsigned short sX[2][4096];   // 2 bufs x 8 KB
  __shared__ int sJlab[256];

  const int tid  = threadIdx.x;
  const int lane = tid & 63;
  const int wid  = tid >> 6;
  const int ag   = blockIdx.x & 31;
  const int ch   = blockIdx.x >> 5;
  const int i0w  = ag * 128 + wid * 32;
  const int l15  = lane & 15;
  const int hi_l = lane >> 4;
  const int rbase = hi_l * 4;
  const int koff  = hi_l * 8;
  const int j0ch  = ch * 256;
  const int srow  = lane & 31;                    // staging row within panel
  const int sk0   = wid * 32 + (lane >> 5) * 8;   // staging k for shot 0 (H=lane>>5)

  sJlab[tid] = labels[j0ch + tid];

  half8 Ax[2][4];
#pragma unroll
  for (int at = 0; at < 2; ++at) {
    const size_t ab = (size_t)(i0w + at * 16 + l15) * DD + koff;
#pragma unroll
    for (int s = 0; s < 4; ++s)
      Ax[at][s] = *reinterpret_cast<const half8*>(xf + ab + s * 32);
  }
  int labA[2][4];
#pragma unroll
  for (int at = 0; at < 2; ++at)
#pragma unroll
    for (int r = 0; r < 4; ++r) labA[at][r] = labels[i0w + at * 16 + rbase + r];

  float mp[2][4], mn[2][4], zs[2][4];
#pragma unroll
  for (int at = 0; at < 2; ++at)
#pragma unroll
    for (int r = 0; r < 4; ++r) { mp[at][r] = INFINITY; mn[at][r] = -INFINITY; zs[at][r] = 0.f; }

  { // prologue stage: panel 0 -> buf 0 (2 shots)
    const size_t g0 = (size_t)(j0ch + srow) * DD + sk0;
    gll16(xf + g0,      &sX[0][wid * 1024]);
    gll16(xf + g0 + 16, &sX[0][wid * 1024 + 512]);   // shot 1: H += 2 -> k += 16
  }

#pragma unroll 1
  for (int pp = 0; pp < NP; ++pp) {
    const int cur = pp & 1;
    __syncthreads();
    if (pp + 1 < NP) {
      const size_t g0 = (size_t)(j0ch + (pp + 1) * 32 + srow) * DD + sk0;
      gll16(xf + g0,      &sX[cur ^ 1][wid * 1024]);
      gll16(xf + g0 + 16, &sX[cur ^ 1][wid * 1024 + 512]);
    }

    f32x4 acc[2][2];
#pragma unroll
    for (int at = 0; at < 2; ++at)
#pragma unroll
      for (int t = 0; t < 2; ++t) acc[at][t] = {0.f, 0.f, 0.f, 0.f};
#pragma unroll
    for (int s = 0; s < 4; ++s) {
#pragma unroll
      for (int t = 0; t < 2; ++t) {
        const int ro = (s * 128 + hi_l * 32 + t * 16 + l15) * 8;
        half8 vB = *reinterpret_cast<const half8*>(&sX[cur][ro]);
        acc[0][t] = mfma16h(Ax[0][s], vB, acc[0][t]);
        acc[1][t] = mfma16h(Ax[1][s], vB, acc[1][t]);
      }
    }

#pragma unroll
    for (int t = 0; t < 2; ++t) {
      const int lj   = sJlab[pp * 32 + t * 16 + l15];
      const int jcol = j0ch + pp * 32 + t * 16 + l15;
#pragma unroll
      for (int at = 0; at < 2; ++at)
#pragma unroll
        for (int r = 0; r < 4; ++r) {
          float sim = acc[at][t][r];
          bool same = (lj == labA[at][r]);
          zs[at][r] += __expf(sim * (same ? 0.25f : 0.125f));
          if (same) {
            if (jcol != i0w + at * 16 + rbase + r) mp[at][r] = fminf(mp[at][r], sim);
          } else {
            mn[at][r] = fmaxf(mn[at][r], sim);
          }
        }
    }
  }

#pragma unroll
  for (int at = 0; at < 2; ++at)
#pragma unroll
    for (int r = 0; r < 4; ++r)
#pragma unroll
      for (int m = 1; m < 16; m <<= 1) {
        mp[at][r] = fminf(mp[at][r], __shfl_xor(mp[at][r], m));
        mn[at][r] = fmaxf(mn[at][r], __shfl_xor(mn[at][r], m));
        zs[at][r] += __shfl_xor(zs[at][r], m);
      }
  if (l15 == 0) {
#pragma unroll
    for (int at = 0; at < 2; ++at)
#pragma unroll
      for (int r = 0; r < 4; ++r) {
        const int i_r = i0w + at * 16 + rbase + r;
        mpP[ch * BB + i_r] = mp[at][r];
        mnP[ch * BB + i_r] = mn[at][r];
        zsP[ch * BB + i_r] = zs[at][r];
      }
  }
}

// ============ kR: merge chunk partials -> per-row stats (+ zero counter) ===
__global__ __launch_bounds__(256) void kR(
    const float* __restrict__ mpP, const float* __restrict__ mnP,
    const float* __restrict__ zsP,
    float* __restrict__ mpg, float* __restrict__ mng, float* __restrict__ zsg,
    int* __restrict__ cnt)
{
  const int i = blockIdx.x * 256 + threadIdx.x;
  if (i == 0) *cnt = 0;
  float a = INFINITY, b = -INFINITY, c = 0.f;
#pragma unroll
  for (int ch = 0; ch < NCH; ++ch) {
    a = fminf(a, mpP[ch * BB + i]);
    b = fmaxf(b, mnP[ch * BB + i]);
    c += zsP[ch * BB + i];
  }
  mpg[i] = a; mng[i] = b; zsg[i] = c;
}

// ============ kB: batch+teacher Gram chunk -> zt/wv/ps/ns partials =========
__global__ __launch_bounds__(TB, 2) void kB(
    const unsigned short* __restrict__ xf, const unsigned short* __restrict__ yf,
    const int* __restrict__ labels,
    const float* __restrict__ mpg, const float* __restrict__ mng,
    float* __restrict__ ztP, float* __restrict__ wvP,
    float* __restrict__ psP, float* __restrict__ nsP)
{
  __shared__ unsigned short sB[2][8192];   // 2 bufs x (X 8KB + Y 8KB) = 32 KB
  __shared__ int sJlab[256];

  const int tid  = threadIdx.x;
  const int lane = tid & 63;
  const int wid  = tid >> 6;
  const int ag   = blockIdx.x & 31;
  const int ch   = blockIdx.x >> 5;
  const int i0w  = ag * 128 + wid * 32;
  const int l15  = lane & 15;
  const int hi_l = lane >> 4;
  const int rbase = hi_l * 4;
  const int koff  = hi_l * 8;
  const int j0ch  = ch * 256;
  const int srow  = lane & 31;
  const int sk0   = wid * 32 + (lane >> 5) * 8;

  sJlab[tid] = labels[j0ch + tid];

  half8 Ax[2][4], Ay[2][4];
#pragma unroll
  for (int at = 0; at < 2; ++at) {
    const size_t ab = (size_t)(i0w + at * 16 + l15) * DD + koff;
#pragma unroll
    for (int s = 0; s < 4; ++s) {
      Ax[at][s] = *reinterpret_cast<const half8*>(xf + ab + s * 32);
      Ay[at][s] = *reinterpret_cast<const half8*>(yf + ab + s * 32);
    }
  }
  int labA[2][4]; float mpA[2][4], mnA[2][4];
#pragma unroll
  for (int at = 0; at < 2; ++at)
#pragma unroll
    for (int r = 0; r < 4; ++r) {
      const int i_r = i0w + at * 16 + rbase + r;
      labA[at][r] = labels[i_r];
      mpA[at][r]  = mpg[i_r];
      mnA[at][r]  = mng[i_r];
    }

  float zt[2][4], wv[2][4], ps[2][4], ns[2][4];
#pragma unroll
  for (int at = 0; at < 2; ++at)
#pragma unroll
    for (int r = 0; r < 4; ++r) { zt[at][r] = 0.f; wv[at][r] = 0.f; ps[at][r] = 0.f; ns[at][r] = 0.f; }

  { // prologue stage: panel 0 -> buf 0 (X then Y, 2 shots each)
    const size_t g0 = (size_t)(j0ch + srow) * DD + sk0;
    gll16(xf + g0,      &sB[0][wid * 1024]);
    gll16(xf + g0 + 16, &sB[0][wid * 1024 + 512]);
    gll16(yf + g0,      &sB[0][4096 + wid * 1024]);
    gll16(yf + g0 + 16, &sB[0][4096 + wid * 1024 + 512]);
  }

#pragma unroll 1
  for (int pp = 0; pp < NP; ++pp) {
    const int cur = pp & 1;
    __syncthreads();
    if (pp + 1 < NP) {
      const size_t g0 = (size_t)(j0ch + (pp + 1) * 32 + srow) * DD + sk0;
      gll16(xf + g0,      &sB[cur ^ 1][wid * 1024]);
      gll16(xf + g0 + 16, &sB[cur ^ 1][wid * 1024 + 512]);
      gll16(yf + g0,      &sB[cur ^ 1][4096 + wid * 1024]);
      gll16(yf + g0 + 16, &sB[cur ^ 1][4096 + wid * 1024 + 512]);
    }

    f32x4 aS[2][2], aT[2][2];
#pragma unroll
    for (int at = 0; at < 2; ++at)
#pragma unroll
      for (int t = 0; t < 2; ++t) { aS[at][t] = {0.f,0.f,0.f,0.f}; aT[at][t] = {0.f,0.f,0.f,0.f}; }
#pragma unroll
    for (int s = 0; s < 4; ++s) {
#pragma unroll
      for (int t = 0; t < 2; ++t) {
        const int ro = (s * 128 + hi_l * 32 + t * 16 + l15) * 8;
        half8 vX = *reinterpret_cast<const half8*>(&sB[cur][ro]);
        half8 vY = *reinterpret_cast<const half8*>(&sB[cur][4096 + ro]);
        aS[0][t] = mfma16h(Ax[0][s], vX, aS[0][t]);
        aS[1][t] = mfma16h(Ax[1][s], vX, aS[1][t]);
        aT[0][t] = mfma16h(Ay[0][s], vY, aT[0][t]);
        aT[1][t] = mfma16h(Ay[1][s], vY, aT[1][t]);
      }
    }

#pragma unroll
    for (int t = 0; t < 2; ++t) {
      const int lj   = sJlab[pp * 32 + t * 16 + l15];
      const int jcol = j0ch + pp * 32 + t * 16 + l15;
#pragma unroll
      for (int at = 0; at < 2; ++at)
#pragma unroll
        for (int r = 0; r < 4; ++r) {
          float sim = aS[at][t][r], ts0 = aT[at][t][r];
          bool same = (lj == labA[at][r]);
          float sc = same ? 0.25f : 0.125f;
          float s  = sim * sc;
          float ts = ts0 * sc;
          float et = __expf(ts);
          zt[at][r] += et;
          wv[at][r] += et * (ts - s);
          if (same) {
            if (jcol != i0w + at * 16 + rbase + r && (sim - MARGIN < mnA[at][r]))
              ps[at][r] += __expf(-POS_W * (sim - THRESH));
          } else {
            if (sim + MARGIN > mpA[at][r])
              ns[at][r] += __expf(NEG_W * (sim - THRESH));
          }
        }
    }
  }

#pragma unroll
  for (int at = 0; at < 2; ++at)
#pragma unroll
    for (int r = 0; r < 4; ++r)
#pragma unroll
      for (int m = 1; m < 16; m <<= 1) {
        zt[at][r] += __shfl_xor(zt[at][r], m);
        wv[at][r] += __shfl_xor(wv[at][r], m);
        ps[at][r] += __shfl_xor(ps[at][r], m);
        ns[at][r] += __shfl_xor(ns[at][r], m);
      }
  if (l15 == 0) {
#pragma unroll
    for (int at = 0; at < 2; ++at)
#pragma unroll
      for (int r = 0; r < 4; ++r) {
        const int i_r = i0w + at * 16 + rbase + r;
        ztP[ch * BB + i_r] = zt[at][r];
        wvP[ch * BB + i_r] = wv[at][r];
        psP[ch * BB + i_r] = ps[at][r];
        nsP[ch * BB + i_r] = ns[at][r];
      }
  }
}

// ============ kD: finalize; last block merges (deterministic) ==============
__global__ __launch_bounds__(512) void kD(
    const float* __restrict__ zsg, const float* __restrict__ ztP,
    const float* __restrict__ wvP, const float* __restrict__ psP,
    const float* __restrict__ nsP, const int* __restrict__ epoch,
    double* __restrict__ rkP, double* __restrict__ kdP, int* __restrict__ nvP,
    int* __restrict__ cnt, float* __restrict__ out)
{
  __shared__ double sR[8], sK[8];
  __shared__ int    sN[8];
  const int tid = threadIdx.x;
  const int lane = tid & 63;
  const int wid = tid >> 6;
  const int i = blockIdx.x * 512 + tid;

  float zt = 0.f, wv = 0.f, ps = 0.f, ns = 0.f;
#pragma unroll
  for (int c = 0; c < NCH; ++c) {
    zt += ztP[c * BB + i];
    wv += wvP[c * BB + i];
    ps += psP[c * BB + i];
    ns += nsP[c * BB + i];
  }
  float zs = zsg[i];
  double kd = (double)(wv / zt + __logf(zs) - __logf(zt));
  double rank = 0.0; int nv = 0;
  if (ps > 0.f && ns > 0.f) {
    rank = (double)(log1pf(ps) * 0.5f + log1pf(ns) * 0.025f);
    nv = 1;
  }
#pragma unroll
  for (int o = 32; o; o >>= 1) {
    rank += __shfl_xor(rank, o);
    kd   += __shfl_xor(kd, o);
    nv   += __shfl_xor(nv, o);
  }
  if (lane == 0) { sR[wid] = rank; sK[wid] = kd; sN[wid] = nv; }
  __syncthreads();
  if (tid == 0) {
    double R_ = 0.0, K_ = 0.0; int N_ = 0;
    for (int w = 0; w < 8; ++w) { R_ += sR[w]; K_ += sK[w]; N_ += sN[w]; }
    rkP[blockIdx.x] = R_;
    kdP[blockIdx.x] = K_;
    nvP[blockIdx.x] = N_;
    __threadfence();
    int old = atomicAdd(cnt, 1);
    if (old == 7) {
      __threadfence();
      double RT = 0.0, KT = 0.0; int NT = 0;
      for (int b = 0; b < 8; ++b) { RT += rkP[b]; KT += kdP[b]; NT += nvP[b]; }
      double loss_rank = RT / (double)(NT < 1 ? 1 : NT);
      double loss_kd   = KT / (double)BB;
      double wgt = (double)epoch[0] * 0.16;   // epoch/100 * ALPHA * TAU^2
      out[0] = (float)(loss_rank + wgt * loss_kd);
      out[1] = (float)loss_rank;
      out[2] = (float)loss_kd;
      *cnt = 0;   // reset for next replay
    }
  }
}

extern "C" void kernel_launch(void* const* d_in, const int* in_sizes, int n_in,
                              void* d_out, int out_size, void* d_ws, size_t ws_size,
                              hipStream_t stream)
{
  (void)in_sizes; (void)n_in; (void)out_size; (void)ws_size;
  const float* batch   = (const float*)d_in[0];
  const float* teacher = (const float*)d_in[1];
  const int*   labels  = (const int*)d_in[2];
  const int*   epoch   = (const int*)d_in[3];
  float* out = (float*)d_out;

  char* w = (char*)d_ws;
  const size_t MB = 1048576;
  unsigned short* xf = (unsigned short*)(w + 0 * MB);   // 1 MB each
  unsigned short* yf = (unsigned short*)(w + 1 * MB);
  const size_t PCH = (size_t)NCH * BB * sizeof(float);  // 256 KB
  float* mpP = (float*)(w + 2 * MB + 0 * PCH);
  float* mnP = (float*)(w + 2 * MB + 1 * PCH);
  float* zsP = (float*)(w + 2 * MB + 2 * PCH);
  float* ztP = (float*)(w + 2 * MB + 3 * PCH);
  float* wvP = (float*)(w + 2 * MB + 4 * PCH);
  float* psP = (float*)(w + 2 * MB + 5 * PCH);
  float* nsP = (float*)(w + 2 * MB + 6 * PCH);
  float* mpg = (float*)(w + 4 * MB);
  float* mng = (float*)(w + 4 * MB + 16384);
  float* zsg = (float*)(w + 4 * MB + 32768);
  double* rkP = (double*)(w + 4 * MB + 49152);
  double* kdP = (double*)(w + 4 * MB + 49152 + 64);
  int*    nvP = (int*)(w + 4 * MB + 49152 + 128);
  int*    cnt = (int*)(w + 4 * MB + 49152 + 192);

  k0<<<dim3(BB * DD / 4 / 256), dim3(256), 0, stream>>>(batch, teacher, xf, yf);
  kA<<<dim3(32 * NCH), dim3(TB), 0, stream>>>(xf, labels, mpP, mnP, zsP);
  kR<<<dim3(BB / 256), dim3(256), 0, stream>>>(mpP, mnP, zsP, mpg, mng, zsg, cnt);
  kB<<<dim3(32 * NCH), dim3(TB), 0, stream>>>(xf, yf, labels, mpg, mng,
                                              ztP, wvP, psP, nsP);
  kD<<<dim3(8), dim3(512), 0, stream>>>(zsg, ztP, wvP, psP, nsP, epoch,
                                        rkP, kdP, nvP, cnt, out);
}

// Round 12
// 59.303 us; speedup vs baseline: 21.1087x; 1.0705x over previous
//
#include <hip/hip_runtime.h>
#include <hip/hip_fp16.h>
#include <math.h>

#define BB  4096
#define DD  128
#define NCH 16             // j-chunks (256 j each)
#define NP  8              // panels per chunk (32 j each)
#define TB  256            // threads per block (4 waves)

typedef __attribute__((ext_vector_type(8))) _Float16 half8;
typedef __attribute__((ext_vector_type(4))) float f32x4;

constexpr float POS_W  = 2.0f;
constexpr float NEG_W  = 40.0f;
constexpr float MARGIN = 0.1f;
constexpr float THRESH = 0.5f;

__device__ __forceinline__ unsigned short f2h(float f) {
  __half h = __float2half(f);
  return __half_as_ushort(h);
}
__device__ __forceinline__ f32x4 mfma16h(half8 a, half8 b, f32x4 c) {
  return __builtin_amdgcn_mfma_f32_16x16x32_f16(a, b, c, 0, 0, 0);
}
// async global->LDS, 16B per lane; lds dest = uniform base + lane*16
__device__ __forceinline__ void gll16(const void* g, void* l) {
  __builtin_amdgcn_global_load_lds(
      (const __attribute__((address_space(1))) void*)g,
      (__attribute__((address_space(3))) void*)l, 16, 0, 0);
}

// ============ k0: fp32 -> fp16 for batch & teacher (+ zero cnt) ============
__global__ __launch_bounds__(256) void k0(
    const float* __restrict__ b, const float* __restrict__ t,
    unsigned short* __restrict__ xf, unsigned short* __restrict__ yf,
    int* __restrict__ cnt)
{
  const int i = blockIdx.x * 256 + threadIdx.x;   // < BB*DD/4 = 131072
  if (i == 0) *cnt = 0;
  {
    float4 v = reinterpret_cast<const float4*>(b)[i];
    ushort4 h;
    h.x = f2h(v.x); h.y = f2h(v.y); h.z = f2h(v.z); h.w = f2h(v.w);
    reinterpret_cast<ushort4*>(xf)[i] = h;
  }
  {
    float4 v = reinterpret_cast<const float4*>(t)[i];
    ushort4 h;
    h.x = f2h(v.x); h.y = f2h(v.y); h.z = f2h(v.z); h.w = f2h(v.w);
    reinterpret_cast<ushort4*>(yf)[i] = h;
  }
}

// LDS panel layout (per array, 32-j panel, 8 KB = 512 slots of 16B):
//   slot = S*128 + H*32 + J   (S=k-step, H=k-sub, J=j)  <-> row J, k=[S*32+H*8,+8)
// staging: wave wid covers S=wid; shot s2: dest slots wid*128 + s2*64 + lane
//   source row = j0p + (lane&31), k = wid*32 + (s2*2 + (lane>>5))*8
// fragment read (k-step s, j-tile t): slot = s*128 + hi_l*32 + t*16 + l15

// ============ kG1: batch+teacher Grams -> zs/mp/mn/zt/wv chunk partials ====
__global__ __launch_bounds__(TB, 2) void kG1(
    const unsigned short* __restrict__ xf, const unsigned short* __restrict__ yf,
    const int* __restrict__ labels,
    float* __restrict__ zsP, float* __restrict__ mpP, float* __restrict__ mnP,
    float* __restrict__ ztP, float* __restrict__ wvP)
{
  __shared__ unsigned short sB[2][8192];   // 2 bufs x (X 8KB + Y 8KB) = 32 KB
  __shared__ int sJlab[256];

  const int tid  = threadIdx.x;
  const int lane = tid & 63;
  const int wid  = tid >> 6;
  const int ag   = blockIdx.x & 31;
  const int ch   = blockIdx.x >> 5;
  const int i0w  = ag * 128 + wid * 32;
  const int l15  = lane & 15;
  const int hi_l = lane >> 4;
  const int rbase = hi_l * 4;
  const int koff  = hi_l * 8;
  const int j0ch  = ch * 256;
  const int srow  = lane & 31;
  const int sk0   = wid * 32 + (lane >> 5) * 8;

  sJlab[tid] = labels[j0ch + tid];

  half8 Ax[2][4], Ay[2][4];
#pragma unroll
  for (int at = 0; at < 2; ++at) {
    const size_t ab = (size_t)(i0w + at * 16 + l15) * DD + koff;
#pragma unroll
    for (int s = 0; s < 4; ++s) {
      Ax[at][s] = *reinterpret_cast<const half8*>(xf + ab + s * 32);
      Ay[at][s] = *reinterpret_cast<const half8*>(yf + ab + s * 32);
    }
  }
  int labA[2][4];
#pragma unroll
  for (int at = 0; at < 2; ++at)
#pragma unroll
    for (int r = 0; r < 4; ++r) labA[at][r] = labels[i0w + at * 16 + rbase + r];

  float zs[2][4], mp[2][4], mn[2][4], zt[2][4], wv[2][4];
#pragma unroll
  for (int at = 0; at < 2; ++at)
#pragma unroll
    for (int r = 0; r < 4; ++r) {
      zs[at][r] = 0.f; mp[at][r] = INFINITY; mn[at][r] = -INFINITY;
      zt[at][r] = 0.f; wv[at][r] = 0.f;
    }

  { // prologue stage: panel 0 -> buf 0 (X then Y, 2 shots each)
    const size_t g0 = (size_t)(j0ch + srow) * DD + sk0;
    gll16(xf + g0,      &sB[0][wid * 1024]);
    gll16(xf + g0 + 16, &sB[0][wid * 1024 + 512]);
    gll16(yf + g0,      &sB[0][4096 + wid * 1024]);
    gll16(yf + g0 + 16, &sB[0][4096 + wid * 1024 + 512]);
  }

#pragma unroll 1
  for (int pp = 0; pp < NP; ++pp) {
    const int cur = pp & 1;
    __syncthreads();
    if (pp + 1 < NP) {
      const size_t g0 = (size_t)(j0ch + (pp + 1) * 32 + srow) * DD + sk0;
      gll16(xf + g0,      &sB[cur ^ 1][wid * 1024]);
      gll16(xf + g0 + 16, &sB[cur ^ 1][wid * 1024 + 512]);
      gll16(yf + g0,      &sB[cur ^ 1][4096 + wid * 1024]);
      gll16(yf + g0 + 16, &sB[cur ^ 1][4096 + wid * 1024 + 512]);
    }

    f32x4 aS[2][2], aT[2][2];
#pragma unroll
    for (int at = 0; at < 2; ++at)
#pragma unroll
      for (int t = 0; t < 2; ++t) { aS[at][t] = {0.f,0.f,0.f,0.f}; aT[at][t] = {0.f,0.f,0.f,0.f}; }
#pragma unroll
    for (int s = 0; s < 4; ++s) {
#pragma unroll
      for (int t = 0; t < 2; ++t) {
        const int ro = (s * 128 + hi_l * 32 + t * 16 + l15) * 8;
        half8 vX = *reinterpret_cast<const half8*>(&sB[cur][ro]);
        half8 vY = *reinterpret_cast<const half8*>(&sB[cur][4096 + ro]);
        aS[0][t] = mfma16h(Ax[0][s], vX, aS[0][t]);
        aS[1][t] = mfma16h(Ax[1][s], vX, aS[1][t]);
        aT[0][t] = mfma16h(Ay[0][s], vY, aT[0][t]);
        aT[1][t] = mfma16h(Ay[1][s], vY, aT[1][t]);
      }
    }

#pragma unroll
    for (int t = 0; t < 2; ++t) {
      const int lj   = sJlab[pp * 32 + t * 16 + l15];
      const int jcol = j0ch + pp * 32 + t * 16 + l15;
#pragma unroll
      for (int at = 0; at < 2; ++at)
#pragma unroll
        for (int r = 0; r < 4; ++r) {
          float sim = aS[at][t][r], tsim = aT[at][t][r];
          bool same = (lj == labA[at][r]);
          float sc = same ? 0.25f : 0.125f;
          float s  = sim * sc;
          float ts = tsim * sc;
          zs[at][r] += __expf(s);
          float et = __expf(ts);
          zt[at][r] += et;
          wv[at][r] += et * (ts - s);
          if (same) {
            if (jcol != i0w + at * 16 + rbase + r) mp[at][r] = fminf(mp[at][r], sim);
          } else {
            mn[at][r] = fmaxf(mn[at][r], sim);
          }
        }
    }
  }

#pragma unroll
  for (int at = 0; at < 2; ++at)
#pragma unroll
    for (int r = 0; r < 4; ++r)
#pragma unroll
      for (int m = 1; m < 16; m <<= 1) {
        zs[at][r] += __shfl_xor(zs[at][r], m);
        mp[at][r] = fminf(mp[at][r], __shfl_xor(mp[at][r], m));
        mn[at][r] = fmaxf(mn[at][r], __shfl_xor(mn[at][r], m));
        zt[at][r] += __shfl_xor(zt[at][r], m);
        wv[at][r] += __shfl_xor(wv[at][r], m);
      }
  if (l15 == 0) {
#pragma unroll
    for (int at = 0; at < 2; ++at)
#pragma unroll
      for (int r = 0; r < 4; ++r) {
        const int i_r = i0w + at * 16 + rbase + r;
        zsP[ch * BB + i_r] = zs[at][r];
        mpP[ch * BB + i_r] = mp[at][r];
        mnP[ch * BB + i_r] = mn[at][r];
        ztP[ch * BB + i_r] = zt[at][r];
        wvP[ch * BB + i_r] = wv[at][r];
      }
  }
}

// ============ kG2: batch Gram -> ps/ns chunk partials (reduces mp/mn) ======
__global__ __launch_bounds__(TB, 3) void kG2(
    const unsigned short* __restrict__ xf,
    const int* __restrict__ labels,
    const float* __restrict__ mpP, const float* __restrict__ mnP,
    float* __restrict__ psP, float* __restrict__ nsP)
{
  __shared__ unsigned short sX[2][4096];   // 2 bufs x 8 KB
  __shared__ int sJlab[256];
  __shared__ float sMPr[128], sMNr[128];

  const int tid  = threadIdx.x;
  const int lane = tid & 63;
  const int wid  = tid >> 6;
  const int ag   = blockIdx.x & 31;
  const int ch   = blockIdx.x >> 5;
  const int i0w  = ag * 128 + wid * 32;
  const int l15  = lane & 15;
  const int hi_l = lane >> 4;
  const int rbase = hi_l * 4;
  const int koff  = hi_l * 8;
  const int j0ch  = ch * 256;
  const int srow  = lane & 31;
  const int sk0   = wid * 32 + (lane >> 5) * 8;

  { // prologue stage: panel 0 -> buf 0 (issue first; hides under reduce)
    const size_t g0 = (size_t)(j0ch + srow) * DD + sk0;
    gll16(xf + g0,      &sX[0][wid * 1024]);
    gll16(xf + g0 + 16, &sX[0][wid * 1024 + 512]);
  }

  sJlab[tid] = labels[j0ch + tid];
  if (tid < 128) {          // block-wide reduce of the 16 chunk partials
    const int aidx = ag * 128 + tid;
    float a = INFINITY, b = -INFINITY;
#pragma unroll
    for (int c = 0; c < NCH; ++c) {
      a = fminf(a, mpP[c * BB + aidx]);
      b = fmaxf(b, mnP[c * BB + aidx]);
    }
    sMPr[tid] = a; sMNr[tid] = b;
  }

  half8 Ax[2][4];
#pragma unroll
  for (int at = 0; at < 2; ++at) {
    const size_t ab = (size_t)(i0w + at * 16 + l15) * DD + koff;
#pragma unroll
    for (int s = 0; s < 4; ++s)
      Ax[at][s] = *reinterpret_cast<const half8*>(xf + ab + s * 32);
  }
  int labA[2][4];
#pragma unroll
  for (int at = 0; at < 2; ++at)
#pragma unroll
    for (int r = 0; r < 4; ++r) labA[at][r] = labels[i0w + at * 16 + rbase + r];

  __syncthreads();          // sMPr/sMNr + sJlab visible (also drains buf0)
  float mpA[2][4], mnA[2][4];
#pragma unroll
  for (int at = 0; at < 2; ++at)
#pragma unroll
    for (int r = 0; r < 4; ++r) {
      const int al = wid * 32 + at * 16 + rbase + r;
      mpA[at][r] = sMPr[al];
      mnA[at][r] = sMNr[al];
    }

  float ps[2][4], ns[2][4];
#pragma unroll
  for (int at = 0; at < 2; ++at)
#pragma unroll
    for (int r = 0; r < 4; ++r) { ps[at][r] = 0.f; ns[at][r] = 0.f; }

#pragma unroll 1
  for (int pp = 0; pp < NP; ++pp) {
    const int cur = pp & 1;
    __syncthreads();
    if (pp + 1 < NP) {
      const size_t g0 = (size_t)(j0ch + (pp + 1) * 32 + srow) * DD + sk0;
      gll16(xf + g0,      &sX[cur ^ 1][wid * 1024]);
      gll16(xf + g0 + 16, &sX[cur ^ 1][wid * 1024 + 512]);
    }

    f32x4 acc[2][2];
#pragma unroll
    for (int at = 0; at < 2; ++at)
#pragma unroll
      for (int t = 0; t < 2; ++t) acc[at][t] = {0.f, 0.f, 0.f, 0.f};
#pragma unroll
    for (int s = 0; s < 4; ++s) {
#pragma unroll
      for (int t = 0; t < 2; ++t) {
        const int ro = (s * 128 + hi_l * 32 + t * 16 + l15) * 8;
        half8 vB = *reinterpret_cast<const half8*>(&sX[cur][ro]);
        acc[0][t] = mfma16h(Ax[0][s], vB, acc[0][t]);
        acc[1][t] = mfma16h(Ax[1][s], vB, acc[1][t]);
      }
    }

#pragma unroll
    for (int t = 0; t < 2; ++t) {
      const int lj   = sJlab[pp * 32 + t * 16 + l15];
      const int jcol = j0ch + pp * 32 + t * 16 + l15;
#pragma unroll
      for (int at = 0; at < 2; ++at)
#pragma unroll
        for (int r = 0; r < 4; ++r) {
          float sim = acc[at][t][r];
          bool same = (lj == labA[at][r]);
          if (same) {
            if (jcol != i0w + at * 16 + rbase + r && (sim - MARGIN < mnA[at][r]))
              ps[at][r] += __expf(-POS_W * (sim - THRESH));
          } else {
            if (sim + MARGIN > mpA[at][r])
              ns[at][r] += __expf(NEG_W * (sim - THRESH));
          }
        }
    }
  }

#pragma unroll
  for (int at = 0; at < 2; ++at)
#pragma unroll
    for (int r = 0; r < 4; ++r)
#pragma unroll
      for (int m = 1; m < 16; m <<= 1) {
        ps[at][r] += __shfl_xor(ps[at][r], m);
        ns[at][r] += __shfl_xor(ns[at][r], m);
      }
  if (l15 == 0) {
#pragma unroll
    for (int at = 0; at < 2; ++at)
#pragma unroll
      for (int r = 0; r < 4; ++r) {
        const int i_r = i0w + at * 16 + rbase + r;
        psP[ch * BB + i_r] = ps[at][r];
        nsP[ch * BB + i_r] = ns[at][r];
      }
  }
}

// ============ kD: finalize; last block merges (deterministic) ==============
__global__ __launch_bounds__(512) void kD(
    const float* __restrict__ zsP, const float* __restrict__ ztP,
    const float* __restrict__ wvP, const float* __restrict__ psP,
    const float* __restrict__ nsP, const int* __restrict__ epoch,
    double* __restrict__ rkP, double* __restrict__ kdP, int* __restrict__ nvP,
    int* __restrict__ cnt, float* __restrict__ out)
{
  __shared__ double sR[8], sK[8];
  __shared__ int    sN[8];
  const int tid = threadIdx.x;
  const int lane = tid & 63;
  const int wid = tid >> 6;
  const int i = blockIdx.x * 512 + tid;

  float zs = 0.f, zt = 0.f, wv = 0.f, ps = 0.f, ns = 0.f;
#pragma unroll
  for (int c = 0; c < NCH; ++c) {
    zs += zsP[c * BB + i];
    zt += ztP[c * BB + i];
    wv += wvP[c * BB + i];
    ps += psP[c * BB + i];
    ns += nsP[c * BB + i];
  }
  double kd = (double)(wv / zt + __logf(zs) - __logf(zt));
  double rank = 0.0; int nv = 0;
  if (ps > 0.f && ns > 0.f) {
    rank = (double)(log1pf(ps) * 0.5f + log1pf(ns) * 0.025f);
    nv = 1;
  }
#pragma unroll
  for (int o = 32; o; o >>= 1) {
    rank += __shfl_xor(rank, o);
    kd   += __shfl_xor(kd, o);
    nv   += __shfl_xor(nv, o);
  }
  if (lane == 0) { sR[wid] = rank; sK[wid] = kd; sN[wid] = nv; }
  __syncthreads();
  if (tid == 0) {
    double R_ = 0.0, K_ = 0.0; int N_ = 0;
    for (int w = 0; w < 8; ++w) { R_ += sR[w]; K_ += sK[w]; N_ += sN[w]; }
    rkP[blockIdx.x] = R_;
    kdP[blockIdx.x] = K_;
    nvP[blockIdx.x] = N_;
    __threadfence();
    int old = atomicAdd(cnt, 1);
    if (old == 7) {
      __threadfence();
      double RT = 0.0, KT = 0.0; int NT = 0;
      for (int b = 0; b < 8; ++b) { RT += rkP[b]; KT += kdP[b]; NT += nvP[b]; }
      double loss_rank = RT / (double)(NT < 1 ? 1 : NT);
      double loss_kd   = KT / (double)BB;
      double wgt = (double)epoch[0] * 0.16;   // epoch/100 * ALPHA * TAU^2
      out[0] = (float)(loss_rank + wgt * loss_kd);
      out[1] = (float)loss_rank;
      out[2] = (float)loss_kd;
      *cnt = 0;   // reset for next replay
    }
  }
}

extern "C" void kernel_launch(void* const* d_in, const int* in_sizes, int n_in,
                              void* d_out, int out_size, void* d_ws, size_t ws_size,
                              hipStream_t stream)
{
  (void)in_sizes; (void)n_in; (void)out_size; (void)ws_size;
  const float* batch   = (const float*)d_in[0];
  const float* teacher = (const float*)d_in[1];
  const int*   labels  = (const int*)d_in[2];
  const int*   epoch   = (const int*)d_in[3];
  float* out = (float*)d_out;

  char* w = (char*)d_ws;
  const size_t MB = 1048576;
  unsigned short* xf = (unsigned short*)(w + 0 * MB);   // 1 MB each
  unsigned short* yf = (unsigned short*)(w + 1 * MB);
  const size_t PCH = (size_t)NCH * BB * sizeof(float);  // 256 KB
  float* zsP = (float*)(w + 2 * MB + 0 * PCH);
  float* mpP = (float*)(w + 2 * MB + 1 * PCH);
  float* mnP = (float*)(w + 2 * MB + 2 * PCH);
  float* ztP = (float*)(w + 2 * MB + 3 * PCH);
  float* wvP = (float*)(w + 2 * MB + 4 * PCH);
  float* psP = (float*)(w + 2 * MB + 5 * PCH);
  float* nsP = (float*)(w + 2 * MB + 6 * PCH);
  double* rkP = (double*)(w + 4 * MB);
  double* kdP = (double*)(w + 4 * MB + 64);
  int*    nvP = (int*)(w + 4 * MB + 128);
  int*    cnt = (int*)(w + 4 * MB + 192);

  k0<<<dim3(BB * DD / 4 / 256), dim3(256), 0, stream>>>(batch, teacher, xf, yf, cnt);
  kG1<<<dim3(32 * NCH), dim3(TB), 0, stream>>>(xf, yf, labels,
                                               zsP, mpP, mnP, ztP, wvP);
  kG2<<<dim3(32 * NCH), dim3(TB), 0, stream>>>(xf, labels, mpP, mnP, psP, nsP);
  kD<<<dim3(8), dim3(512), 0, stream>>>(zsP, ztP, wvP, psP, nsP, epoch,
                                        rkP, kdP, nvP, cnt, out);
}